// Round 1
// baseline (999.794 us; speedup 1.0000x reference)
//
#include <hip/hip_runtime.h>
#include <stdint.h>
#include <math.h>

// Problem constants
#define BN 4
#define VN 16384
#define KN 16
#define HN 4
#define NN (BN*VN)          // 65536 nodes total
#define NEGC (-1.0e9f)

typedef __attribute__((ext_vector_type(8))) short short8;
typedef __attribute__((ext_vector_type(4))) float floatx4;
typedef unsigned short u16;

// ---------- workspace layout (bytes) ----------
#define OFF_H      0ull                     // h       fp32 [NN][64]   16 MB
#define OFF_T      16777216ull              // t_all   bf16 [NN][256]  32 MB
#define OFF_M      50331648ull              // m       fp32 [NN][64]   16 MB
#define OFF_ZR     67108864ull              // zr      bf16 [NN][128]  16 MB
#define OFF_SSRC   83886080ull              // s_src   fp32 [NN][4]     1 MB
#define OFF_SDST   84934656ull              // s_dst   fp32 [NN][4]     1 MB
#define OFF_NW     85983232ull              // node_w  fp32 [NN]      256 KB
#define OFF_INFLOW 86245376ull              // inflow  fp32 [BN][VN+1]
#define OFF_PG     86507776ull              // packed W_gat   32 KB
#define OFF_PZR    (OFF_PG  + 32768ull)     // packed Wz|Wr/Uz|Ur 32 KB
#define OFF_PC     (OFF_PZR + 32768ull)     // packed Wc/Uc   16 KB
#define OFF_PE1    (OFF_PC  + 16384ull)     // packed W_enc1 (K padded to 64) 8 KB
#define OFF_PE2    (OFF_PE1 + 8192ull)      // packed W_enc2  8 KB
#define OFF_PD1    (OFF_PE2 + 8192ull)      // packed W_dec1  8 KB
// total ws use ~86.6 MB

__device__ __forceinline__ u16 f2bf(float x){
  union { float f; unsigned int u; } c; c.f = x;
  unsigned int r = c.u + 0x7fffu + ((c.u >> 16) & 1u);
  return (u16)(r >> 16);
}
__device__ __forceinline__ float bf2f(u16 s){
  union { unsigned int u; float f; } c; c.u = ((unsigned int)s) << 16;
  return c.f;
}
__device__ __forceinline__ float sigm(float x){ return 1.0f/(1.0f+expf(-x)); }

union S8 { short8 v; u16 u[8]; };

// ================= weight pack kernel =================
// packed layout (both A and B fragments use this): for matrix Mat[K][Dout],
// flat elem e = ((ng*CN + c)*64 + lane)*8 + j  holds Mat[k][n] as bf16 with
// k = c*32 + (lane>>4)*8 + j,  n = ng*16 + (lane&15),  CN = K/32.
__global__ __launch_bounds__(256) void k_pack(
    const float* __restrict__ Wg,  const float* __restrict__ Wz, const float* __restrict__ Uz,
    const float* __restrict__ Wr,  const float* __restrict__ Ur, const float* __restrict__ Wc,
    const float* __restrict__ Uc,  const float* __restrict__ We1, const float* __restrict__ We2,
    const float* __restrict__ Wd1,
    u16* __restrict__ pg, u16* __restrict__ pzr, u16* __restrict__ pc,
    u16* __restrict__ pe1, u16* __restrict__ pe2, u16* __restrict__ pd1)
{
  int e = blockIdx.x*256 + threadIdx.x;   // 0 .. 53247
  int el; u16* dst; int CN; int region;
  if      (e < 16384){ el = e;        dst = pg;  CN = 2; region = 0; }
  else if (e < 32768){ el = e-16384;  dst = pzr; CN = 4; region = 1; }
  else if (e < 40960){ el = e-32768;  dst = pc;  CN = 4; region = 2; }
  else if (e < 45056){ el = e-40960;  dst = pe1; CN = 2; region = 3; }
  else if (e < 49152){ el = e-45056;  dst = pe2; CN = 2; region = 4; }
  else               { el = e-49152;  dst = pd1; CN = 2; region = 5; }
  int j    = el & 7;
  int lane = (el >> 3) & 63;
  int rest = el >> 9;
  int c  = rest % CN;
  int ng = rest / CN;
  int k  = c*32 + (lane>>4)*8 + j;
  int n  = ng*16 + (lane&15);
  float val = 0.0f;
  if (region == 0){                 // W_gat [H][64][64], n = hd*64+d
    val = Wg[(size_t)(n>>6)*4096 + k*64 + (n&63)];
  } else if (region == 1){          // [m|h] @ [[Wz Wr],[Uz Ur]]
    if (n < 64) val = (k<64) ? Wz[k*64+n]      : Uz[(k-64)*64+n];
    else        val = (k<64) ? Wr[k*64+(n-64)] : Ur[(k-64)*64+(n-64)];
  } else if (region == 2){          // [m|r*h] @ [[Wc],[Uc]]
    val = (k<64) ? Wc[k*64+n] : Uc[(k-64)*64+n];
  } else if (region == 3){          // W_enc1 [34][64], K padded to 64 with zeros
    val = (k<34) ? We1[k*64+n] : 0.0f;
  } else if (region == 4){
    val = We2[k*64+n];
  } else {
    val = Wd1[k*64+n];
  }
  dst[el] = f2bf(val);
}

// ================= shared GEMM helpers =================
// Block = 128 threads = 2 waves; block tile = 128 rows; wave tile = 64 rows x 64 cols.
// A tile in LDS, fragment-major: idx (short8 units) = (rg*CN + c)*64 + (lane) ,
// where for element (row,k): rg=row>>4, c=k>>5, lane = ((k>>3)&3)*16 + (row&15), j=k&7.

template<int CN>
__device__ __forceinline__ void load_b(const u16* p, int chunk, int lane, short8 Bf[CN][4]){
  const short8* P = (const short8*)p;
  #pragma unroll
  for (int c=0;c<CN;c++)
    #pragma unroll
    for (int ng=0; ng<4; ng++)
      Bf[c][ng] = P[((chunk*4+ng)*CN + c)*64 + lane];
}

template<int CN>
__device__ __forceinline__ void mfma_tile(const short8* A, const short8 Bf[CN][4],
                                          floatx4 acc[4][4], int wave, int lane){
  #pragma unroll
  for (int c=0;c<CN;c++){
    #pragma unroll
    for (int mg=0;mg<4;mg++){
      short8 a = A[((wave*4+mg)*CN + c)*64 + lane];
      #pragma unroll
      for (int ng=0;ng<4;ng++)
        acc[mg][ng] = __builtin_amdgcn_mfma_f32_16x16x32_bf16(a, Bf[c][ng], acc[mg][ng], 0, 0, 0);
    }
  }
}

__device__ __forceinline__ void zero_acc(floatx4 acc[4][4]){
  #pragma unroll
  for (int mg=0;mg<4;mg++)
    #pragma unroll
    for (int ng=0;ng<4;ng++){
      floatx4 z = {0.f,0.f,0.f,0.f};
      acc[mg][ng] = z;
    }
}

// ================= encoder =================
// h = tanh( tanh([emb|feat] @ We1 + b1) @ We2 + b2 ), two chained MFMA gemms.
__global__ __launch_bounds__(128) void k_enc(
    const float* __restrict__ emb, const float* __restrict__ feat,
    const u16* __restrict__ pe1, const u16* __restrict__ pe2,
    const float* __restrict__ be1, const float* __restrict__ be2,
    float* __restrict__ hout)
{
  __shared__ short8 A1[1024];
  __shared__ short8 A2[1024];
  const int tid = threadIdx.x;
  const int n0  = blockIdx.x * 128;
  // stage x = [emb(32) | feat(2) | 0...] padded to K=64
  for (int it=0; it<8; ++it){
    int slot = it*128 + tid;
    int row = slot >> 3, jc = slot & 7;
    S8 w;
    if (jc < 4){
      const float* s = emb + (size_t)(n0+row)*32 + jc*8;
      #pragma unroll
      for (int j=0;j<8;j++) w.u[j] = f2bf(s[j]);
    } else if (jc == 4){
      const float* s = feat + (size_t)(n0+row)*2;
      w.u[0] = f2bf(s[0]); w.u[1] = f2bf(s[1]);
      #pragma unroll
      for (int j=2;j<8;j++) w.u[j] = 0;
    } else {
      #pragma unroll
      for (int j=0;j<8;j++) w.u[j] = 0;
    }
    A1[((row>>4)*2 + (jc>>2))*64 + (jc&3)*16 + (row&15)] = w.v;
  }
  __syncthreads();
  const int wave = tid>>6, lane = tid&63, q = lane>>4, ml = lane&15;

  short8 Bf[2][4];
  load_b<2>(pe1, 0, lane, Bf);
  floatx4 acc[4][4];
  zero_acc(acc);
  mfma_tile<2>(A1, Bf, acc, wave, lane);

  // epilogue 1: tanh, write h1 into A2 in fragment layout (own wave's rows only)
  u16* A2s = (u16*)A2;
  #pragma unroll
  for (int mg=0;mg<4;mg++){
    #pragma unroll
    for (int r=0;r<4;r++){
      int row_l = wave*64 + mg*16 + q*4 + r;
      #pragma unroll
      for (int ng=0;ng<4;ng++){
        int k2 = ng*16 + ml;
        float v = tanhf(acc[mg][ng][r] + be1[k2]);
        int c2 = k2>>5, q2=(k2>>3)&3, j2=k2&7;
        A2s[ (((row_l>>4)*2 + c2)*64 + q2*16 + (row_l&15))*8 + j2 ] = f2bf(v);
      }
    }
  }
  __syncthreads();

  load_b<2>(pe2, 0, lane, Bf);
  zero_acc(acc);
  mfma_tile<2>(A2, Bf, acc, wave, lane);
  #pragma unroll
  for (int mg=0;mg<4;mg++)
    #pragma unroll
    for (int r=0;r<4;r++){
      int row = n0 + wave*64 + mg*16 + q*4 + r;
      #pragma unroll
      for (int ng=0;ng<4;ng++){
        int col = ng*16 + ml;
        hout[(size_t)row*64 + col] = tanhf(acc[mg][ng][r] + be2[col]);
      }
    }
}

// ================= t = h @ W_gat (all 4 heads) + s_src/s_dst dots =================
__global__ __launch_bounds__(128) void k_t(
    const float* __restrict__ h, const u16* __restrict__ pg,
    const float* __restrict__ asrc, const float* __restrict__ adst,
    u16* __restrict__ tall, float* __restrict__ ssrc, float* __restrict__ sdst)
{
  __shared__ short8 A[1024];
  const int tid = threadIdx.x;
  const int n0  = blockIdx.x * 128;
  for (int it=0; it<8; ++it){
    int slot = it*128 + tid;
    int row = slot >> 3, jc = slot & 7;
    const float* s = h + (size_t)(n0+row)*64 + jc*8;
    S8 w;
    #pragma unroll
    for (int j=0;j<8;j++) w.u[j] = f2bf(s[j]);
    A[((row>>4)*2 + (jc>>2))*64 + (jc&3)*16 + (row&15)] = w.v;
  }
  __syncthreads();
  const int wave = tid>>6, lane = tid&63, q = lane>>4, ml = lane&15;

  for (int chunk=0; chunk<4; ++chunk){       // chunk == head
    short8 Bf[2][4];
    load_b<2>(pg, chunk, lane, Bf);
    floatx4 acc[4][4];
    zero_acc(acc);
    mfma_tile<2>(A, Bf, acc, wave, lane);

    float as[4], ad[4];
    #pragma unroll
    for (int ng=0;ng<4;ng++){
      as[ng] = asrc[chunk*64 + ng*16 + ml];
      ad[ng] = adst[chunk*64 + ng*16 + ml];
    }
    #pragma unroll
    for (int mg=0;mg<4;mg++){
      #pragma unroll
      for (int r=0;r<4;r++){
        int row = n0 + wave*64 + mg*16 + q*4 + r;
        float ps = 0.f, pd = 0.f;
        #pragma unroll
        for (int ng=0;ng<4;ng++){
          float v = acc[mg][ng][r];
          tall[(size_t)row*256 + chunk*64 + ng*16 + ml] = f2bf(v);
          ps += v*as[ng]; pd += v*ad[ng];
        }
        #pragma unroll
        for (int s=1;s<16;s<<=1){ ps += __shfl_xor(ps, s, 64); pd += __shfl_xor(pd, s, 64); }
        if (ml == 0){ ssrc[row*4 + chunk] = ps; sdst[row*4 + chunk] = pd; }
      }
    }
  }
}

// ================= attention + aggregate + tanh(m) =================
// one wave per node; lane = hd*16+k for scores, lane = d for aggregation
__global__ __launch_bounds__(256) void k_attn(
    const int* __restrict__ adj, const u16* __restrict__ tall,
    const float* __restrict__ ssrc, const float* __restrict__ sdst,
    float* __restrict__ m)
{
  const int wave = threadIdx.x>>6, lane = threadIdx.x&63;
  const int nid = blockIdx.x*4 + wave;
  const int b = nid >> 14;
  const int hd = lane>>4, k = lane&15;
  int u = adj[(size_t)nid*16 + k];
  float sc = (u == VN) ? NEGC : (ssrc[nid*4 + hd] + sdst[((size_t)b*VN + u)*4 + hd]);
  float mx = sc;
  #pragma unroll
  for (int s=1;s<16;s<<=1) mx = fmaxf(mx, __shfl_xor(mx, s, 64));
  float ex = expf(sc - mx);
  float sm = ex;
  #pragma unroll
  for (int s=1;s<16;s<<=1) sm += __shfl_xor(sm, s, 64);
  float attn = ex / sm;

  float agg = 0.f;
  for (int k2=0;k2<16;k2++){
    int u2 = __shfl(u, k2, 64);
    if (u2 != VN){
      const u16* tb = tall + ((size_t)b*VN + u2)*256;
      #pragma unroll
      for (int hd2=0;hd2<4;hd2++){
        float av = __shfl(attn, hd2*16 + k2, 64);
        agg += av * bf2f(tb[hd2*64 + lane]);
      }
    }
  }
  m[(size_t)nid*64 + lane] = tanhf(agg * 0.25f);
}

// ================= GRU pass 1: z,r = sigmoid([m|h] @ [[Wz Wr],[Uz Ur]] + b) =================
__global__ __launch_bounds__(128) void k_gru1(
    const float* __restrict__ m, const float* __restrict__ h,
    const u16* __restrict__ pzr, const float* __restrict__ bz, const float* __restrict__ br,
    u16* __restrict__ zr)
{
  __shared__ short8 A[2048];
  const int tid = threadIdx.x;
  const int n0  = blockIdx.x * 128;
  for (int it=0; it<16; ++it){
    int slot = it*128 + tid;
    int row = slot >> 4, jc = slot & 15;
    const float* s = (jc < 8) ? (m + (size_t)(n0+row)*64 + jc*8)
                              : (h + (size_t)(n0+row)*64 + (jc-8)*8);
    S8 w;
    #pragma unroll
    for (int j=0;j<8;j++) w.u[j] = f2bf(s[j]);
    A[((row>>4)*4 + (jc>>2))*64 + (jc&3)*16 + (row&15)] = w.v;
  }
  __syncthreads();
  const int wave = tid>>6, lane = tid&63, q = lane>>4, ml = lane&15;

  for (int chunk=0; chunk<2; ++chunk){       // 0: z, 1: r
    short8 Bf[4][4];
    load_b<4>(pzr, chunk, lane, Bf);
    floatx4 acc[4][4];
    zero_acc(acc);
    mfma_tile<4>(A, Bf, acc, wave, lane);
    const float* bias = chunk ? br : bz;
    #pragma unroll
    for (int mg=0;mg<4;mg++)
      #pragma unroll
      for (int r=0;r<4;r++){
        int row = n0 + wave*64 + mg*16 + q*4 + r;
        #pragma unroll
        for (int ng=0;ng<4;ng++){
          int col = ng*16 + ml;
          zr[(size_t)row*128 + chunk*64 + col] = f2bf(sigm(acc[mg][ng][r] + bias[col]));
        }
      }
  }
}

// ================= GRU pass 2: c = tanh([m|r*h]@[[Wc],[Uc]]+bc); h = (1-z)h + z*c =================
__global__ __launch_bounds__(128) void k_gru2(
    const float* __restrict__ m, float* __restrict__ h,
    const u16* __restrict__ zr, const u16* __restrict__ pc_,
    const float* __restrict__ bc_)
{
  __shared__ short8 A[2048];
  const int tid = threadIdx.x;
  const int n0  = blockIdx.x * 128;
  for (int it=0; it<16; ++it){
    int slot = it*128 + tid;
    int row = slot >> 4, jc = slot & 15;
    S8 w;
    if (jc < 8){
      const float* s = m + (size_t)(n0+row)*64 + jc*8;
      #pragma unroll
      for (int j=0;j<8;j++) w.u[j] = f2bf(s[j]);
    } else {
      int kk = (jc-8)*8;
      const float* hs = h + (size_t)(n0+row)*64 + kk;
      const u16*  rs = zr + (size_t)(n0+row)*128 + 64 + kk;
      #pragma unroll
      for (int j=0;j<8;j++) w.u[j] = f2bf(hs[j] * bf2f(rs[j]));
    }
    A[((row>>4)*4 + (jc>>2))*64 + (jc&3)*16 + (row&15)] = w.v;
  }
  __syncthreads();
  const int wave = tid>>6, lane = tid&63, q = lane>>4, ml = lane&15;

  short8 Bf[4][4];
  load_b<4>(pc_, 0, lane, Bf);
  floatx4 acc[4][4];
  zero_acc(acc);
  mfma_tile<4>(A, Bf, acc, wave, lane);
  #pragma unroll
  for (int mg=0;mg<4;mg++)
    #pragma unroll
    for (int r=0;r<4;r++){
      int row = n0 + wave*64 + mg*16 + q*4 + r;
      #pragma unroll
      for (int ng=0;ng<4;ng++){
        int col = ng*16 + ml;
        float cv = tanhf(acc[mg][ng][r] + bc_[col]);
        float zv = bf2f(zr[(size_t)row*128 + col]);
        float ho = h[(size_t)row*64 + col];
        h[(size_t)row*64 + col] = (1.f - zv)*ho + zv*cv;
      }
    }
}

// ================= decoder: node_w = tanh(h@Wd1+b1)@Wd2 + b2 =================
__global__ __launch_bounds__(128) void k_dec(
    const float* __restrict__ h, const u16* __restrict__ pd1,
    const float* __restrict__ bd1, const float* __restrict__ Wd2, const float* __restrict__ bd2,
    float* __restrict__ nodew)
{
  __shared__ short8 A[1024];
  const int tid = threadIdx.x;
  const int n0  = blockIdx.x * 128;
  for (int it=0; it<8; ++it){
    int slot = it*128 + tid;
    int row = slot >> 3, jc = slot & 7;
    const float* s = h + (size_t)(n0+row)*64 + jc*8;
    S8 w;
    #pragma unroll
    for (int j=0;j<8;j++) w.u[j] = f2bf(s[j]);
    A[((row>>4)*2 + (jc>>2))*64 + (jc&3)*16 + (row&15)] = w.v;
  }
  __syncthreads();
  const int wave = tid>>6, lane = tid&63, q = lane>>4, ml = lane&15;

  short8 Bf[2][4];
  load_b<2>(pd1, 0, lane, Bf);
  floatx4 acc[4][4];
  zero_acc(acc);
  mfma_tile<2>(A, Bf, acc, wave, lane);

  float wd2l[4];
  #pragma unroll
  for (int ng=0;ng<4;ng++) wd2l[ng] = Wd2[ng*16 + ml];
  float b2 = bd2[0];
  #pragma unroll
  for (int mg=0;mg<4;mg++)
    #pragma unroll
    for (int r=0;r<4;r++){
      int row = n0 + wave*64 + mg*16 + q*4 + r;
      float ps = 0.f;
      #pragma unroll
      for (int ng=0;ng<4;ng++)
        ps += tanhf(acc[mg][ng][r] + bd1[ng*16+ml]) * wd2l[ng];
      #pragma unroll
      for (int s=1;s<16;s<<=1) ps += __shfl_xor(ps, s, 64);
      if (ml == 0) nodew[row] = ps + b2;
    }
}

// ================= edge softmax + flow0 + init =================
__global__ __launch_bounds__(256) void k_pw(
    const int* __restrict__ adj, const float* __restrict__ nodew, const float* __restrict__ dem,
    float* __restrict__ normw, float* __restrict__ f0,
    float* __restrict__ inflow, float* __restrict__ cost)
{
  int e = blockIdx.x*256 + threadIdx.x;     // 0 .. B*V*K-1
  int node = e >> 4;
  int b = node >> 14;
  int u = adj[e];
  float pw = (u == VN) ? NEGC : nodew[(size_t)b*VN + u];
  float mx = pw;
  #pragma unroll
  for (int s=1;s<16;s<<=1) mx = fmaxf(mx, __shfl_xor(mx, s, 64));
  float ex = expf(pw - mx);
  float sm = ex;
  #pragma unroll
  for (int s=1;s<16;s<<=1) sm += __shfl_xor(sm, s, 64);
  float nw = ex / sm;
  normw[e] = nw;
  float d = dem[node];
  f0[e] = nw * fmaxf(-d, 0.f);
  if (e < BN*(VN+1)) inflow[e] = 0.f;
  if (e < BN) cost[e] = 0.f;
}

// ================= flow solver =================
__global__ __launch_bounds__(256) void k_scatter(
    const int* __restrict__ adj, const float* __restrict__ fsrc, float* __restrict__ inflow)
{
  int e = blockIdx.x*256 + threadIdx.x;
  int b = e >> 18;
  int u = adj[e];
  atomicAdd(inflow + (size_t)b*(VN+1) + u, fsrc[e]);
}

__global__ __launch_bounds__(256) void k_update(
    const float* __restrict__ dem, const float* __restrict__ normw,
    float* __restrict__ inflow, float* __restrict__ fdst)
{
  int e = blockIdx.x*256 + threadIdx.x;
  int node = e >> 4, k = e & 15;
  int b = node >> 14, v = node & (VN-1);
  float infl = inflow[(size_t)b*(VN+1) + v];   // all 16 lanes of this node read
  if (k == 0) inflow[(size_t)b*(VN+1) + v] = 0.f;   // same-wave, issued after load
  float d = dem[node];
  fdst[e] = normw[e] * fmaxf(infl - d, 0.f);
}

__global__ __launch_bounds__(256) void k_cost(const float* __restrict__ f, float* __restrict__ cost)
{
  int node = blockIdx.x*256 + threadIdx.x;
  const floatx4* fp = (const floatx4*)(f + (size_t)node*16);
  float ss = 0.f;
  #pragma unroll
  for (int i=0;i<4;i++){
    floatx4 v = fp[i];
    ss += v[0]*v[0] + v[1]*v[1] + v[2]*v[2] + v[3]*v[3];
  }
  #pragma unroll
  for (int s=1;s<64;s<<=1) ss += __shfl_xor(ss, s, 64);
  __shared__ float part[4];
  if ((threadIdx.x & 63) == 0) part[threadIdx.x>>6] = ss;
  __syncthreads();
  if (threadIdx.x == 0){
    float t = part[0]+part[1]+part[2]+part[3];
    atomicAdd(cost + (node >> 14), t);
  }
}

// ================= launcher =================
extern "C" void kernel_launch(void* const* d_in, const int* in_sizes, int n_in,
                              void* d_out, int out_size, void* d_ws, size_t ws_size,
                              hipStream_t stream)
{
  const float* emb  = (const float*)d_in[0];
  const float* feat = (const float*)d_in[1];
  const float* dem  = (const float*)d_in[2];
  const int*   adj  = (const int*)  d_in[3];
  // d_in[4] flow_indices: unused (random, unrelated to adj); d_in[5] num_nodes: compile-time
  const float* We1 = (const float*)d_in[6];
  const float* be1 = (const float*)d_in[7];
  const float* We2 = (const float*)d_in[8];
  const float* be2 = (const float*)d_in[9];
  const float* Wg  = (const float*)d_in[10];
  const float* asrc= (const float*)d_in[11];
  const float* adst= (const float*)d_in[12];
  const float* Wz  = (const float*)d_in[13];
  const float* Uz  = (const float*)d_in[14];
  const float* bz  = (const float*)d_in[15];
  const float* Wr  = (const float*)d_in[16];
  const float* Ur  = (const float*)d_in[17];
  const float* br  = (const float*)d_in[18];
  const float* Wc  = (const float*)d_in[19];
  const float* Uc  = (const float*)d_in[20];
  const float* bc  = (const float*)d_in[21];
  const float* Wd1 = (const float*)d_in[22];
  const float* bd1 = (const float*)d_in[23];
  const float* Wd2 = (const float*)d_in[24];
  const float* bd2 = (const float*)d_in[25];

  char* ws = (char*)d_ws;
  float* h     = (float*)(ws + OFF_H);
  u16*   tall  = (u16*)  (ws + OFF_T);
  float* m     = (float*)(ws + OFF_M);
  u16*   zr    = (u16*)  (ws + OFF_ZR);
  float* ssrc  = (float*)(ws + OFF_SSRC);
  float* sdst  = (float*)(ws + OFF_SDST);
  float* nodew = (float*)(ws + OFF_NW);
  float* inflow= (float*)(ws + OFF_INFLOW);
  u16* pg  = (u16*)(ws + OFF_PG);
  u16* pzr = (u16*)(ws + OFF_PZR);
  u16* pc  = (u16*)(ws + OFF_PC);
  u16* pe1 = (u16*)(ws + OFF_PE1);
  u16* pe2 = (u16*)(ws + OFF_PE2);
  u16* pd1 = (u16*)(ws + OFF_PD1);

  float* out0 = (float*)d_out;            // flow   [B,V,K]
  float* out1 = out0 + 1048576;           // flow_cost [B]
  float* out2 = out0 + 1048580;           // norm_w [B,V,K]
  float* out3 = out0 + 2097156;           // pflow  [B,V,K]

  k_pack<<<208, 256, 0, stream>>>(Wg, Wz, Uz, Wr, Ur, Wc, Uc, We1, We2, Wd1,
                                  pg, pzr, pc, pe1, pe2, pd1);
  k_enc<<<512, 128, 0, stream>>>(emb, feat, pe1, pe2, be1, be2, h);

  for (int l=0; l<2; ++l){
    k_t   <<<512, 128, 0, stream>>>(h, pg, asrc, adst, tall, ssrc, sdst);
    k_attn<<<16384, 256, 0, stream>>>(adj, tall, ssrc, sdst, m);
    k_gru1<<<512, 128, 0, stream>>>(m, h, pzr, bz, br, zr);
    k_gru2<<<512, 128, 0, stream>>>(m, h, zr, pc, bc);
  }

  k_dec<<<512, 128, 0, stream>>>(h, pd1, bd1, Wd2, bd2, nodew);
  k_pw <<<4096, 256, 0, stream>>>(adj, nodew, dem, out2, out0, inflow, out1);

  float* fb[2] = { out0, out3 };   // f_even -> out0 (flow=f10), f_odd -> out3 (pflow=f9)
  for (int i=1; i<=10; ++i){
    k_scatter<<<4096, 256, 0, stream>>>(adj, fb[(i-1)&1], inflow);
    k_update <<<4096, 256, 0, stream>>>(dem, out2, inflow, fb[i&1]);
  }
  k_cost<<<256, 256, 0, stream>>>(out0, out1);
}

// Round 2
// 982.267 us; speedup vs baseline: 1.0178x; 1.0178x over previous
//
#include <hip/hip_runtime.h>
#include <stdint.h>
#include <math.h>

// Problem constants
#define BN 4
#define VN 16384
#define KN 16
#define HN 4
#define NN (BN*VN)          // 65536 nodes total
#define NEGC (-1.0e9f)

typedef __attribute__((ext_vector_type(8))) short short8;
typedef __attribute__((ext_vector_type(4))) float floatx4;
typedef unsigned short u16;

// ---------- workspace layout (bytes) ----------
#define OFF_H      0ull                     // h       fp32 [NN][64]   16 MB
#define OFF_T      16777216ull              // t_all   bf16 [NN][256]  32 MB
#define OFF_M      50331648ull              // m       fp32 [NN][64]   16 MB
#define OFF_SSRC   67108864ull              // s_src   fp32 [NN][4]     1 MB
#define OFF_SDST   68157440ull              // s_dst   fp32 [NN][4]     1 MB
#define OFF_NW     69206016ull              // node_w  fp32 [NN]      256 KB
#define OFF_INFLOW 69468160ull              // inflow  fp32 [2][BN][VN+1]  524,320 B
#define OFF_PG     70254592ull              // packed W_gat   32 KB
#define OFF_PZR    (OFF_PG  + 32768ull)     // packed Wz|Wr/Uz|Ur 32 KB
#define OFF_PC     (OFF_PZR + 32768ull)     // packed Wc/Uc   16 KB
#define OFF_PE1    (OFF_PC  + 16384ull)     // packed W_enc1 (K padded to 64) 8 KB
#define OFF_PE2    (OFF_PE1 + 8192ull)      // packed W_enc2  8 KB
#define OFF_PD1    (OFF_PE2 + 8192ull)      // packed W_dec1  8 KB
// total ws use ~67.2 MB

__device__ __forceinline__ u16 f2bf(float x){
  union { float f; unsigned int u; } c; c.f = x;
  unsigned int r = c.u + 0x7fffu + ((c.u >> 16) & 1u);
  return (u16)(r >> 16);
}
__device__ __forceinline__ float bf2f(u16 s){
  union { unsigned int u; float f; } c; c.u = ((unsigned int)s) << 16;
  return c.f;
}
__device__ __forceinline__ float sigm(float x){ return 1.0f/(1.0f+expf(-x)); }

union S8 { short8 v; u16 u[8]; };

// ================= weight pack kernel =================
// packed layout: flat elem e = ((ng*CN + c)*64 + lane)*8 + j holds Mat[k][n],
// k = c*32 + (lane>>4)*8 + j,  n = ng*16 + (lane&15),  CN = K/32.
__global__ __launch_bounds__(256) void k_pack(
    const float* __restrict__ Wg,  const float* __restrict__ Wz, const float* __restrict__ Uz,
    const float* __restrict__ Wr,  const float* __restrict__ Ur, const float* __restrict__ Wc,
    const float* __restrict__ Uc,  const float* __restrict__ We1, const float* __restrict__ We2,
    const float* __restrict__ Wd1,
    u16* __restrict__ pg, u16* __restrict__ pzr, u16* __restrict__ pc,
    u16* __restrict__ pe1, u16* __restrict__ pe2, u16* __restrict__ pd1)
{
  int e = blockIdx.x*256 + threadIdx.x;   // 0 .. 53247
  int el; u16* dst; int CN; int region;
  if      (e < 16384){ el = e;        dst = pg;  CN = 2; region = 0; }
  else if (e < 32768){ el = e-16384;  dst = pzr; CN = 4; region = 1; }
  else if (e < 40960){ el = e-32768;  dst = pc;  CN = 4; region = 2; }
  else if (e < 45056){ el = e-40960;  dst = pe1; CN = 2; region = 3; }
  else if (e < 49152){ el = e-45056;  dst = pe2; CN = 2; region = 4; }
  else               { el = e-49152;  dst = pd1; CN = 2; region = 5; }
  int j    = el & 7;
  int lane = (el >> 3) & 63;
  int rest = el >> 9;
  int c  = rest % CN;
  int ng = rest / CN;
  int k  = c*32 + (lane>>4)*8 + j;
  int n  = ng*16 + (lane&15);
  float val = 0.0f;
  if (region == 0){                 // W_gat [H][64][64], n = hd*64+d
    val = Wg[(size_t)(n>>6)*4096 + k*64 + (n&63)];
  } else if (region == 1){          // [m|h] @ [[Wz Wr],[Uz Ur]]
    if (n < 64) val = (k<64) ? Wz[k*64+n]      : Uz[(k-64)*64+n];
    else        val = (k<64) ? Wr[k*64+(n-64)] : Ur[(k-64)*64+(n-64)];
  } else if (region == 2){          // [m|r*h] @ [[Wc],[Uc]]
    val = (k<64) ? Wc[k*64+n] : Uc[(k-64)*64+n];
  } else if (region == 3){          // W_enc1 [34][64], K padded to 64 with zeros
    val = (k<34) ? We1[k*64+n] : 0.0f;
  } else if (region == 4){
    val = We2[k*64+n];
  } else {
    val = Wd1[k*64+n];
  }
  dst[el] = f2bf(val);
}

// ================= shared GEMM helpers =================
template<int CN>
__device__ __forceinline__ void load_b(const u16* p, int chunk, int lane, short8 Bf[CN][4]){
  const short8* P = (const short8*)p;
  #pragma unroll
  for (int c=0;c<CN;c++)
    #pragma unroll
    for (int ng=0; ng<4; ng++)
      Bf[c][ng] = P[((chunk*4+ng)*CN + c)*64 + lane];
}

template<int CN>
__device__ __forceinline__ void mfma_tile(const short8* A, const short8 Bf[CN][4],
                                          floatx4 acc[4][4], int wave, int lane){
  #pragma unroll
  for (int c=0;c<CN;c++){
    #pragma unroll
    for (int mg=0;mg<4;mg++){
      short8 a = A[((wave*4+mg)*CN + c)*64 + lane];
      #pragma unroll
      for (int ng=0;ng<4;ng++)
        acc[mg][ng] = __builtin_amdgcn_mfma_f32_16x16x32_bf16(a, Bf[c][ng], acc[mg][ng], 0, 0, 0);
    }
  }
}

__device__ __forceinline__ void zero_acc(floatx4 acc[4][4]){
  #pragma unroll
  for (int mg=0;mg<4;mg++)
    #pragma unroll
    for (int ng=0;ng<4;ng++){
      floatx4 z = {0.f,0.f,0.f,0.f};
      acc[mg][ng] = z;
    }
}

// ================= encoder =================
__global__ __launch_bounds__(128) void k_enc(
    const float* __restrict__ emb, const float* __restrict__ feat,
    const u16* __restrict__ pe1, const u16* __restrict__ pe2,
    const float* __restrict__ be1, const float* __restrict__ be2,
    float* __restrict__ hout)
{
  __shared__ short8 A1[1024];
  __shared__ short8 A2[1024];
  const int tid = threadIdx.x;
  const int n0  = blockIdx.x * 128;
  for (int it=0; it<8; ++it){
    int slot = it*128 + tid;
    int row = slot >> 3, jc = slot & 7;
    S8 w;
    if (jc < 4){
      const float* s = emb + (size_t)(n0+row)*32 + jc*8;
      #pragma unroll
      for (int j=0;j<8;j++) w.u[j] = f2bf(s[j]);
    } else if (jc == 4){
      const float* s = feat + (size_t)(n0+row)*2;
      w.u[0] = f2bf(s[0]); w.u[1] = f2bf(s[1]);
      #pragma unroll
      for (int j=2;j<8;j++) w.u[j] = 0;
    } else {
      #pragma unroll
      for (int j=0;j<8;j++) w.u[j] = 0;
    }
    A1[((row>>4)*2 + (jc>>2))*64 + (jc&3)*16 + (row&15)] = w.v;
  }
  __syncthreads();
  const int wave = tid>>6, lane = tid&63, q = lane>>4, ml = lane&15;

  short8 Bf[2][4];
  load_b<2>(pe1, 0, lane, Bf);
  floatx4 acc[4][4];
  zero_acc(acc);
  mfma_tile<2>(A1, Bf, acc, wave, lane);

  u16* A2s = (u16*)A2;
  #pragma unroll
  for (int mg=0;mg<4;mg++){
    #pragma unroll
    for (int r=0;r<4;r++){
      int row_l = wave*64 + mg*16 + q*4 + r;
      #pragma unroll
      for (int ng=0;ng<4;ng++){
        int k2 = ng*16 + ml;
        float v = tanhf(acc[mg][ng][r] + be1[k2]);
        int c2 = k2>>5, q2=(k2>>3)&3, j2=k2&7;
        A2s[ (((row_l>>4)*2 + c2)*64 + q2*16 + (row_l&15))*8 + j2 ] = f2bf(v);
      }
    }
  }
  __syncthreads();

  load_b<2>(pe2, 0, lane, Bf);
  zero_acc(acc);
  mfma_tile<2>(A2, Bf, acc, wave, lane);
  #pragma unroll
  for (int mg=0;mg<4;mg++)
    #pragma unroll
    for (int r=0;r<4;r++){
      int row = n0 + wave*64 + mg*16 + q*4 + r;
      #pragma unroll
      for (int ng=0;ng<4;ng++){
        int col = ng*16 + ml;
        hout[(size_t)row*64 + col] = tanhf(acc[mg][ng][r] + be2[col]);
      }
    }
}

// ================= t = h @ W_gat (4 heads) + s_src/s_dst row dots =================
__global__ __launch_bounds__(128) void k_t(
    const float* __restrict__ h, const u16* __restrict__ pg,
    const float* __restrict__ asrc, const float* __restrict__ adst,
    u16* __restrict__ tall, float* __restrict__ ssrc, float* __restrict__ sdst)
{
  __shared__ short8 A[1024];
  const int tid = threadIdx.x;
  const int n0  = blockIdx.x * 128;
  for (int it=0; it<8; ++it){
    int slot = it*128 + tid;
    int row = slot >> 3, jc = slot & 7;
    const float* s = h + (size_t)(n0+row)*64 + jc*8;
    S8 w;
    #pragma unroll
    for (int j=0;j<8;j++) w.u[j] = f2bf(s[j]);
    A[((row>>4)*2 + (jc>>2))*64 + (jc&3)*16 + (row&15)] = w.v;
  }
  __syncthreads();
  const int wave = tid>>6, lane = tid&63, q = lane>>4, ml = lane&15;

  for (int chunk=0; chunk<4; ++chunk){       // chunk == head
    short8 Bf[2][4];
    load_b<2>(pg, chunk, lane, Bf);
    floatx4 acc[4][4];
    zero_acc(acc);
    mfma_tile<2>(A, Bf, acc, wave, lane);

    float as[4], ad[4];
    #pragma unroll
    for (int ng=0;ng<4;ng++){
      as[ng] = asrc[chunk*64 + ng*16 + ml];
      ad[ng] = adst[chunk*64 + ng*16 + ml];
    }
    #pragma unroll
    for (int mg=0;mg<4;mg++){
      #pragma unroll
      for (int r=0;r<4;r++){
        int row = n0 + wave*64 + mg*16 + q*4 + r;
        float ps = 0.f, pd = 0.f;
        #pragma unroll
        for (int ng=0;ng<4;ng++){
          float v = acc[mg][ng][r];
          tall[(size_t)row*256 + chunk*64 + ng*16 + ml] = f2bf(v);
          ps += v*as[ng]; pd += v*ad[ng];
        }
        #pragma unroll
        for (int s=1;s<16;s<<=1){ ps += __shfl_xor(ps, s, 64); pd += __shfl_xor(pd, s, 64); }
        if (ml == 0){ ssrc[row*4 + chunk] = ps; sdst[row*4 + chunk] = pd; }
      }
    }
  }
}

// ================= attention + aggregate + tanh(m) =================
// one wave per node. scores: lane = hd*16+k. gather: lane l loads uint2 (4 bf16)
// covering head l>>4, d = 4*(l&15)+j  -> whole 512B row in ONE coalesced instr.
__global__ __launch_bounds__(256) void k_attn(
    const int* __restrict__ adj, const u16* __restrict__ tall,
    const float* __restrict__ ssrc, const float* __restrict__ sdst,
    float* __restrict__ m)
{
  const int wave = threadIdx.x>>6, lane = threadIdx.x&63;
  const int nid = blockIdx.x*4 + wave;
  const int b = nid >> 14;
  const int hd = lane>>4;
  int u = adj[(size_t)nid*16 + (lane&15)];
  float sc = (u == VN) ? NEGC : (ssrc[nid*4 + hd] + sdst[((size_t)b*VN + u)*4 + hd]);
  float mx = sc;
  #pragma unroll
  for (int s=1;s<16;s<<=1) mx = fmaxf(mx, __shfl_xor(mx, s, 64));
  float ex = expf(sc - mx);
  float sm = ex;
  #pragma unroll
  for (int s=1;s<16;s<<=1) sm += __shfl_xor(sm, s, 64);
  float attn = ex / sm;

  float a0=0.f, a1=0.f, a2=0.f, a3=0.f;
  const int srcl = lane & 48;
  const uint2* tbase = (const uint2*)(tall + (size_t)b*VN*256);
  #pragma unroll
  for (int k2=0;k2<16;k2++){
    int u2 = __shfl(u, k2, 64);             // wave-uniform -> readlane+s_branch
    float av = __shfl(attn, srcl + k2, 64); // this head's weight for neighbor k2
    if (u2 != VN){
      uint2 w = tbase[(size_t)u2*64 + lane];
      union { unsigned int u; float f; } c0,c1,c2,c3;
      c0.u = w.x << 16; c1.u = w.x & 0xffff0000u;
      c2.u = w.y << 16; c3.u = w.y & 0xffff0000u;
      a0 += av*c0.f; a1 += av*c1.f; a2 += av*c2.f; a3 += av*c3.f;
    }
  }
  // fold 4 head groups: lanes l, l^16, l^32, l^48
  a0 += __shfl_xor(a0,16,64); a0 += __shfl_xor(a0,32,64);
  a1 += __shfl_xor(a1,16,64); a1 += __shfl_xor(a1,32,64);
  a2 += __shfl_xor(a2,16,64); a2 += __shfl_xor(a2,32,64);
  a3 += __shfl_xor(a3,16,64); a3 += __shfl_xor(a3,32,64);
  if (lane < 16){
    floatx4 val;
    val[0] = tanhf(a0*0.25f); val[1] = tanhf(a1*0.25f);
    val[2] = tanhf(a2*0.25f); val[3] = tanhf(a3*0.25f);
    *(floatx4*)(m + (size_t)nid*64 + lane*4) = val;
  }
}

// ================= fused GRU: z, r, c, h-update in one kernel =================
// Order matters: z and r GEMMs read the ORIGINAL [m|h] tile; only then is the
// h-half overwritten with r*h (wave-local rows -> no barrier needed, each
// wave's MFMA reads only its own rows' fragments); then the c GEMM.
__global__ __launch_bounds__(128) void k_gru(
    const float* __restrict__ m, float* __restrict__ h,
    const u16* __restrict__ pzr, const u16* __restrict__ pc_,
    const float* __restrict__ bz, const float* __restrict__ br,
    const float* __restrict__ bc_)
{
  __shared__ short8 A[2048];
  const int tid = threadIdx.x;
  const int n0  = blockIdx.x * 128;
  for (int it=0; it<16; ++it){
    int slot = it*128 + tid;
    int row = slot >> 4, jc = slot & 15;
    const float* s = (jc < 8) ? (m + (size_t)(n0+row)*64 + jc*8)
                              : (h + (size_t)(n0+row)*64 + (jc-8)*8);
    S8 w;
    #pragma unroll
    for (int j=0;j<8;j++) w.u[j] = f2bf(s[j]);
    A[((row>>4)*4 + (jc>>2))*64 + (jc&3)*16 + (row&15)] = w.v;
  }
  __syncthreads();
  const int wave = tid>>6, lane = tid&63, q = lane>>4, ml = lane&15;

  short8 Bf[4][4];

  // ---- z (chunk 0) on original [m|h] ----
  floatx4 zacc[4][4];
  load_b<4>(pzr, 0, lane, Bf);
  zero_acc(zacc);
  mfma_tile<4>(A, Bf, zacc, wave, lane);

  // ---- r (chunk 1) on original [m|h] ----
  floatx4 acc[4][4];
  load_b<4>(pzr, 1, lane, Bf);
  zero_acc(acc);
  mfma_tile<4>(A, Bf, acc, wave, lane);

  // overwrite h-half of own rows with r*h; save h_old in regs
  floatx4 h_old[4][4];
  u16* As = (u16*)A;
  #pragma unroll
  for (int mg=0;mg<4;mg++){
    #pragma unroll
    for (int r=0;r<4;r++){
      int row_l = wave*64 + mg*16 + q*4 + r;
      int row   = n0 + row_l;
      #pragma unroll
      for (int ng=0;ng<4;ng++){
        int col = ng*16 + ml;
        float rv = sigm(acc[mg][ng][r] + br[col]);
        float hv = h[(size_t)row*64 + col];
        h_old[mg][ng][r] = hv;
        int kk = 64 + col;
        int c2 = kk>>5, q2 = (kk>>3)&3, j2 = kk&7;
        As[ (((row_l>>4)*4 + c2)*64 + q2*16 + (row_l&15))*8 + j2 ] = f2bf(hv*rv);
      }
    }
  }
  // no __syncthreads needed: writes above are to this wave's own rows only,
  // and the MFMA below reads only this wave's rows (lgkmcnt orders LDS ops).

  // ---- c (pc chunk 0) on [m | r*h] ----
  load_b<4>(pc_, 0, lane, Bf);
  zero_acc(acc);
  mfma_tile<4>(A, Bf, acc, wave, lane);

  #pragma unroll
  for (int mg=0;mg<4;mg++)
    #pragma unroll
    for (int r=0;r<4;r++){
      int row = n0 + wave*64 + mg*16 + q*4 + r;
      #pragma unroll
      for (int ng=0;ng<4;ng++){
        int col = ng*16 + ml;
        float zv = sigm(zacc[mg][ng][r] + bz[col]);
        float cv = tanhf(acc[mg][ng][r] + bc_[col]);
        float ho = h_old[mg][ng][r];
        h[(size_t)row*64 + col] = (1.f - zv)*ho + zv*cv;
      }
    }
}

// ================= decoder + zero-init of solver buffers =================
__global__ __launch_bounds__(128) void k_dec(
    const float* __restrict__ h, const u16* __restrict__ pd1,
    const float* __restrict__ bd1, const float* __restrict__ Wd2, const float* __restrict__ bd2,
    float* __restrict__ nodew, float* __restrict__ inflow2, float* __restrict__ cost)
{
  // zero both inflow ping-pong buffers (2*BN*(VN+1) floats) + cost accumulator
  {
    int t = blockIdx.x*128 + threadIdx.x;
    for (int idx = t; idx < 2*BN*(VN+1); idx += 512*128) inflow2[idx] = 0.f;
    if (t < BN) cost[t] = 0.f;
  }
  __shared__ short8 A[1024];
  const int tid = threadIdx.x;
  const int n0  = blockIdx.x * 128;
  for (int it=0; it<8; ++it){
    int slot = it*128 + tid;
    int row = slot >> 3, jc = slot & 7;
    const float* s = h + (size_t)(n0+row)*64 + jc*8;
    S8 w;
    #pragma unroll
    for (int j=0;j<8;j++) w.u[j] = f2bf(s[j]);
    A[((row>>4)*2 + (jc>>2))*64 + (jc&3)*16 + (row&15)] = w.v;
  }
  __syncthreads();
  const int wave = tid>>6, lane = tid&63, q = lane>>4, ml = lane&15;

  short8 Bf[2][4];
  load_b<2>(pd1, 0, lane, Bf);
  floatx4 acc[4][4];
  zero_acc(acc);
  mfma_tile<2>(A, Bf, acc, wave, lane);

  float wd2l[4];
  #pragma unroll
  for (int ng=0;ng<4;ng++) wd2l[ng] = Wd2[ng*16 + ml];
  float b2 = bd2[0];
  #pragma unroll
  for (int mg=0;mg<4;mg++)
    #pragma unroll
    for (int r=0;r<4;r++){
      int row = n0 + wave*64 + mg*16 + q*4 + r;
      float ps = 0.f;
      #pragma unroll
      for (int ng=0;ng<4;ng++)
        ps += tanhf(acc[mg][ng][r] + bd1[ng*16+ml]) * wd2l[ng];
      #pragma unroll
      for (int s=1;s<16;s<<=1) ps += __shfl_xor(ps, s, 64);
      if (ml == 0) nodew[row] = ps + b2;
    }
}

// ================= edge softmax + f0 scatter =================
__global__ __launch_bounds__(256) void k_pw(
    const int* __restrict__ adj, const float* __restrict__ nodew, const float* __restrict__ dem,
    float* __restrict__ normw, float* __restrict__ inflow_wr)
{
  int e = blockIdx.x*256 + threadIdx.x;
  int node = e >> 4;
  int b = node >> 14;
  int u = adj[e];
  float pw = (u == VN) ? NEGC : nodew[(size_t)b*VN + u];
  float mx = pw;
  #pragma unroll
  for (int s=1;s<16;s<<=1) mx = fmaxf(mx, __shfl_xor(mx, s, 64));
  float ex = expf(pw - mx);
  float sm = ex;
  #pragma unroll
  for (int s=1;s<16;s<<=1) sm += __shfl_xor(sm, s, 64);
  float nw = ex / sm;
  normw[e] = nw;
  float f0 = nw * fmaxf(-dem[node], 0.f);
  atomicAdd(inflow_wr + (size_t)b*(VN+1) + u, f0);
}

// ================= fused solver iteration =================
// read inflow(f_{i-1}) -> compute f_i in regs -> scatter f_i into other buffer.
// Intermediate flows never touch memory; fout only for i=9 (pflow), i=10 (flow);
// cost reduction fused into i=10.
__global__ __launch_bounds__(256) void k_iter(
    const int* __restrict__ adj, const float* __restrict__ normw,
    const float* __restrict__ dem, float* __restrict__ rd, float* __restrict__ wr,
    float* __restrict__ fout, float* __restrict__ cost)
{
  int e = blockIdx.x*256 + threadIdx.x;
  int k = e & 15, node = e >> 4;
  int b = node >> 14, v = node & (VN-1);
  float infl = rd[(size_t)b*(VN+1) + v];
  if (k == 0) rd[(size_t)b*(VN+1) + v] = 0.f;   // re-zero for reuse as wr next iter
  float fl = normw[e] * fmaxf(infl - dem[node], 0.f);
  int u = adj[e];
  atomicAdd(wr + (size_t)b*(VN+1) + u, fl);
  if (fout) fout[e] = fl;
  if (cost){
    float ss = fl*fl;
    #pragma unroll
    for (int sh=1; sh<64; sh<<=1) ss += __shfl_xor(ss, sh, 64);
    __shared__ float part[4];
    if ((threadIdx.x & 63) == 0) part[threadIdx.x>>6] = ss;
    __syncthreads();
    if (threadIdx.x == 0) atomicAdd(cost + (e>>18), part[0]+part[1]+part[2]+part[3]);
  }
}

// ================= launcher =================
extern "C" void kernel_launch(void* const* d_in, const int* in_sizes, int n_in,
                              void* d_out, int out_size, void* d_ws, size_t ws_size,
                              hipStream_t stream)
{
  const float* emb  = (const float*)d_in[0];
  const float* feat = (const float*)d_in[1];
  const float* dem  = (const float*)d_in[2];
  const int*   adj  = (const int*)  d_in[3];
  const float* We1 = (const float*)d_in[6];
  const float* be1 = (const float*)d_in[7];
  const float* We2 = (const float*)d_in[8];
  const float* be2 = (const float*)d_in[9];
  const float* Wg  = (const float*)d_in[10];
  const float* asrc= (const float*)d_in[11];
  const float* adst= (const float*)d_in[12];
  const float* Wz  = (const float*)d_in[13];
  const float* Uz  = (const float*)d_in[14];
  const float* bz  = (const float*)d_in[15];
  const float* Wr  = (const float*)d_in[16];
  const float* Ur  = (const float*)d_in[17];
  const float* br  = (const float*)d_in[18];
  const float* Wc  = (const float*)d_in[19];
  const float* Uc  = (const float*)d_in[20];
  const float* bc  = (const float*)d_in[21];
  const float* Wd1 = (const float*)d_in[22];
  const float* bd1 = (const float*)d_in[23];
  const float* Wd2 = (const float*)d_in[24];
  const float* bd2 = (const float*)d_in[25];

  char* ws = (char*)d_ws;
  float* h     = (float*)(ws + OFF_H);
  u16*   tall  = (u16*)  (ws + OFF_T);
  float* m     = (float*)(ws + OFF_M);
  float* ssrc  = (float*)(ws + OFF_SSRC);
  float* sdst  = (float*)(ws + OFF_SDST);
  float* nodew = (float*)(ws + OFF_NW);
  float* inflow= (float*)(ws + OFF_INFLOW);     // [2][BN][VN+1]
  u16* pg  = (u16*)(ws + OFF_PG);
  u16* pzr = (u16*)(ws + OFF_PZR);
  u16* pc  = (u16*)(ws + OFF_PC);
  u16* pe1 = (u16*)(ws + OFF_PE1);
  u16* pe2 = (u16*)(ws + OFF_PE2);
  u16* pd1 = (u16*)(ws + OFF_PD1);
  float* ibuf0 = inflow;
  float* ibuf1 = inflow + BN*(VN+1);

  float* out0 = (float*)d_out;            // flow   [B,V,K]  (= f10)
  float* out1 = out0 + 1048576;           // flow_cost [B]
  float* out2 = out0 + 1048580;           // norm_w [B,V,K]
  float* out3 = out0 + 2097156;           // pflow  [B,V,K]  (= f9)

  k_pack<<<208, 256, 0, stream>>>(Wg, Wz, Uz, Wr, Ur, Wc, Uc, We1, We2, Wd1,
                                  pg, pzr, pc, pe1, pe2, pd1);
  k_enc<<<512, 128, 0, stream>>>(emb, feat, pe1, pe2, be1, be2, h);

  for (int l=0; l<2; ++l){
    k_t   <<<512, 128, 0, stream>>>(h, pg, asrc, adst, tall, ssrc, sdst);
    k_attn<<<16384, 256, 0, stream>>>(adj, tall, ssrc, sdst, m);
    k_gru <<<512, 128, 0, stream>>>(m, h, pzr, pc, bz, br, bc);
  }

  k_dec<<<512, 128, 0, stream>>>(h, pd1, bd1, Wd2, bd2, nodew, inflow, out1);
  k_pw <<<4096, 256, 0, stream>>>(adj, nodew, dem, out2, ibuf0);

  for (int i=1; i<=10; ++i){
    float* rdb = (i & 1) ? ibuf0 : ibuf1;
    float* wrb = (i & 1) ? ibuf1 : ibuf0;
    float* fo  = (i==10) ? out0 : ((i==9) ? out3 : nullptr);
    k_iter<<<4096, 256, 0, stream>>>(adj, out2, dem, rdb, wrb, fo,
                                     (i==10) ? out1 : nullptr);
  }
}

// Round 3
// 899.656 us; speedup vs baseline: 1.1113x; 1.0918x over previous
//
#include <hip/hip_runtime.h>
#include <stdint.h>
#include <math.h>

// Problem constants
#define BN 4
#define VN 16384
#define KN 16
#define HN 4
#define NN (BN*VN)          // 65536 nodes total
#define EN (VN*KN)          // 262144 edges per batch
#define NEGC (-1.0e9f)

typedef __attribute__((ext_vector_type(8))) short short8;
typedef __attribute__((ext_vector_type(4))) float floatx4;
typedef unsigned short u16;
typedef unsigned int u32;

// ---------- workspace layout (bytes) ----------
#define OFF_H      0ull                     // h       fp32 [NN][64]   16 MB
#define OFF_T      16777216ull              // t_all   bf16 [NN][256]  32 MB
#define OFF_M      50331648ull              // m       fp32 [NN][64]   16 MB
#define OFF_SSRC   67108864ull              // s_src   fp32 [NN][4]     1 MB
#define OFF_SDST   68157440ull              // s_dst   fp32 [NN][4]     1 MB
#define OFF_NW     69206016ull              // node_w  fp32 [NN]      256 KB
#define OFF_NV     69468160ull              // nv      fp32 [2][NN]   512 KB
#define OFF_CNT    69992448ull              // cnt     u32  [B][VN+1] ~257 KB (pad 262400)
#define OFF_OFFS   70254848ull              // offs    u32  [B][16400] 262400 B
#define OFF_PERM   70517248ull              // csr perm u32 [B][EN]     4 MB
#define OFF_CSRC   74711552ull              // csr src  u16 [B][EN]     2 MB
#define OFF_CSRW   76808704ull              // csr w    f32 [B][EN]     4 MB
#define OFF_PG     81003008ull              // packed W_gat   32 KB
#define OFF_PZR    (OFF_PG  + 32768ull)     // packed Wz|Wr/Uz|Ur 32 KB
#define OFF_PC     (OFF_PZR + 32768ull)     // packed Wc/Uc   16 KB
#define OFF_PE1    (OFF_PC  + 16384ull)     // packed W_enc1 (K padded to 64) 8 KB
#define OFF_PE2    (OFF_PE1 + 8192ull)      // packed W_enc2  8 KB
#define OFF_PD1    (OFF_PE2 + 8192ull)      // packed W_dec1  8 KB
// total ws use ~81.1 MB

__device__ __forceinline__ u16 f2bf(float x){
  union { float f; unsigned int u; } c; c.f = x;
  unsigned int r = c.u + 0x7fffu + ((c.u >> 16) & 1u);
  return (u16)(r >> 16);
}
__device__ __forceinline__ float bf2f(u16 s){
  union { unsigned int u; float f; } c; c.u = ((unsigned int)s) << 16;
  return c.f;
}
__device__ __forceinline__ float sigm(float x){ return 1.0f/(1.0f+expf(-x)); }

union S8 { short8 v; u16 u[8]; };

// ================= CSR inverse-adjacency build (NO global atomics) =================
// pass 1: per-batch LDS histogram of targets
__global__ __launch_bounds__(1024) void k_csr_count(const int* __restrict__ adj, u32* __restrict__ cnt)
{
  __shared__ u32 c[VN+1];
  const int b = blockIdx.x;
  for (int i=threadIdx.x;i<VN+1;i+=1024) c[i]=0u;
  __syncthreads();
  const int* a = adj + (size_t)b*EN;
  for (int i=threadIdx.x;i<EN;i+=1024) atomicAdd(&c[a[i]], 1u);  // bin VN collects masked
  __syncthreads();
  for (int i=threadIdx.x;i<VN+1;i+=1024) cnt[b*(VN+1)+i]=c[i];
}

// pass 2: exclusive prefix over v (one block per batch)
__global__ __launch_bounds__(1024) void k_scan(const u32* __restrict__ cnt, u32* __restrict__ offs)
{
  __shared__ u32 part[1024];
  const int b = blockIdx.x, t = threadIdx.x;
  const u32* c = cnt + b*(VN+1);
  u32 loc[16];
  u32 s = 0u;
  #pragma unroll
  for (int j=0;j<16;j++){ loc[j]=s; s += c[t*16+j]; }
  part[t]=s; __syncthreads();
  for (int d=1; d<1024; d<<=1){
    u32 v = (t>=d)? part[t-d] : 0u;
    __syncthreads();
    part[t]+=v;
    __syncthreads();
  }
  u32 base = (t>0)? part[t-1] : 0u;
  u32* o = offs + b*16400;
  #pragma unroll
  for (int j=0;j<16;j++) o[t*16+j] = base + loc[j];
  if (t==1023) o[VN] = part[1023];
}

// pass 3: placement via per-batch LDS cursors
__global__ __launch_bounds__(1024) void k_csr_place(
    const int* __restrict__ adj, const u32* __restrict__ offs,
    u32* __restrict__ perm, u16* __restrict__ csrc)
{
  __shared__ u32 cur[VN];
  const int b = blockIdx.x;
  const u32* o = offs + b*16400;
  for (int i=threadIdx.x;i<VN;i+=1024) cur[i]=o[i];
  __syncthreads();
  const int* a = adj + (size_t)b*EN;
  u32* pb = perm + (size_t)b*EN;
  u16* sb = csrc + (size_t)b*EN;
  for (int i=threadIdx.x;i<EN;i+=1024){
    int t = a[i];
    if (t < VN){
      u32 pos = atomicAdd(&cur[t], 1u);
      pb[pos] = (u32)i;
      sb[pos] = (u16)(i >> 4);
    }
  }
}

// pass 4 (after normw known): csr_w[i] = normw[perm[i]]
__global__ __launch_bounds__(256) void k_reorder(
    const u32* __restrict__ perm, const u32* __restrict__ offs,
    const float* __restrict__ normw, float* __restrict__ csrw)
{
  int i = blockIdx.x*256 + threadIdx.x;   // 0..4*EN-1
  int b = i >> 18;
  u32 tot = offs[b*16400 + VN];
  u32 loc = (u32)(i & (EN-1));
  if (loc < tot) csrw[i] = normw[(size_t)b*EN + perm[i]];
}

// ================= weight pack kernel =================
__global__ __launch_bounds__(256) void k_pack(
    const float* __restrict__ Wg,  const float* __restrict__ Wz, const float* __restrict__ Uz,
    const float* __restrict__ Wr,  const float* __restrict__ Ur, const float* __restrict__ Wc,
    const float* __restrict__ Uc,  const float* __restrict__ We1, const float* __restrict__ We2,
    const float* __restrict__ Wd1,
    u16* __restrict__ pg, u16* __restrict__ pzr, u16* __restrict__ pc,
    u16* __restrict__ pe1, u16* __restrict__ pe2, u16* __restrict__ pd1)
{
  int e = blockIdx.x*256 + threadIdx.x;   // 0 .. 53247
  int el; u16* dst; int CN; int region;
  if      (e < 16384){ el = e;        dst = pg;  CN = 2; region = 0; }
  else if (e < 32768){ el = e-16384;  dst = pzr; CN = 4; region = 1; }
  else if (e < 40960){ el = e-32768;  dst = pc;  CN = 4; region = 2; }
  else if (e < 45056){ el = e-40960;  dst = pe1; CN = 2; region = 3; }
  else if (e < 49152){ el = e-45056;  dst = pe2; CN = 2; region = 4; }
  else               { el = e-49152;  dst = pd1; CN = 2; region = 5; }
  int j    = el & 7;
  int lane = (el >> 3) & 63;
  int rest = el >> 9;
  int c  = rest % CN;
  int ng = rest / CN;
  int k  = c*32 + (lane>>4)*8 + j;
  int n  = ng*16 + (lane&15);
  float val = 0.0f;
  if (region == 0){                 // W_gat [H][64][64], n = hd*64+d
    val = Wg[(size_t)(n>>6)*4096 + k*64 + (n&63)];
  } else if (region == 1){          // [m|h] @ [[Wz Wr],[Uz Ur]]
    if (n < 64) val = (k<64) ? Wz[k*64+n]      : Uz[(k-64)*64+n];
    else        val = (k<64) ? Wr[k*64+(n-64)] : Ur[(k-64)*64+(n-64)];
  } else if (region == 2){          // [m|r*h] @ [[Wc],[Uc]]
    val = (k<64) ? Wc[k*64+n] : Uc[(k-64)*64+n];
  } else if (region == 3){          // W_enc1 [34][64], K padded to 64 with zeros
    val = (k<34) ? We1[k*64+n] : 0.0f;
  } else if (region == 4){
    val = We2[k*64+n];
  } else {
    val = Wd1[k*64+n];
  }
  dst[el] = f2bf(val);
}

// ================= shared GEMM helpers =================
template<int CN>
__device__ __forceinline__ void load_b(const u16* p, int chunk, int lane, short8 Bf[CN][4]){
  const short8* P = (const short8*)p;
  #pragma unroll
  for (int c=0;c<CN;c++)
    #pragma unroll
    for (int ng=0; ng<4; ng++)
      Bf[c][ng] = P[((chunk*4+ng)*CN + c)*64 + lane];
}

template<int CN>
__device__ __forceinline__ void mfma_tile(const short8* A, const short8 Bf[CN][4],
                                          floatx4 acc[4][4], int wave, int lane){
  #pragma unroll
  for (int c=0;c<CN;c++){
    #pragma unroll
    for (int mg=0;mg<4;mg++){
      short8 a = A[((wave*4+mg)*CN + c)*64 + lane];
      #pragma unroll
      for (int ng=0;ng<4;ng++)
        acc[mg][ng] = __builtin_amdgcn_mfma_f32_16x16x32_bf16(a, Bf[c][ng], acc[mg][ng], 0, 0, 0);
    }
  }
}

__device__ __forceinline__ void zero_acc(floatx4 acc[4][4]){
  #pragma unroll
  for (int mg=0;mg<4;mg++)
    #pragma unroll
    for (int ng=0;ng<4;ng++){
      floatx4 z = {0.f,0.f,0.f,0.f};
      acc[mg][ng] = z;
    }
}

// ================= encoder =================
__global__ __launch_bounds__(128) void k_enc(
    const float* __restrict__ emb, const float* __restrict__ feat,
    const u16* __restrict__ pe1, const u16* __restrict__ pe2,
    const float* __restrict__ be1, const float* __restrict__ be2,
    float* __restrict__ hout)
{
  __shared__ short8 A1[1024];
  __shared__ short8 A2[1024];
  const int tid = threadIdx.x;
  const int n0  = blockIdx.x * 128;
  for (int it=0; it<8; ++it){
    int slot = it*128 + tid;
    int row = slot >> 3, jc = slot & 7;
    S8 w;
    if (jc < 4){
      const float* s = emb + (size_t)(n0+row)*32 + jc*8;
      #pragma unroll
      for (int j=0;j<8;j++) w.u[j] = f2bf(s[j]);
    } else if (jc == 4){
      const float* s = feat + (size_t)(n0+row)*2;
      w.u[0] = f2bf(s[0]); w.u[1] = f2bf(s[1]);
      #pragma unroll
      for (int j=2;j<8;j++) w.u[j] = 0;
    } else {
      #pragma unroll
      for (int j=0;j<8;j++) w.u[j] = 0;
    }
    A1[((row>>4)*2 + (jc>>2))*64 + (jc&3)*16 + (row&15)] = w.v;
  }
  __syncthreads();
  const int wave = tid>>6, lane = tid&63, q = lane>>4, ml = lane&15;

  short8 Bf[2][4];
  load_b<2>(pe1, 0, lane, Bf);
  floatx4 acc[4][4];
  zero_acc(acc);
  mfma_tile<2>(A1, Bf, acc, wave, lane);

  u16* A2s = (u16*)A2;
  #pragma unroll
  for (int mg=0;mg<4;mg++){
    #pragma unroll
    for (int r=0;r<4;r++){
      int row_l = wave*64 + mg*16 + q*4 + r;
      #pragma unroll
      for (int ng=0;ng<4;ng++){
        int k2 = ng*16 + ml;
        float v = tanhf(acc[mg][ng][r] + be1[k2]);
        int c2 = k2>>5, q2=(k2>>3)&3, j2=k2&7;
        A2s[ (((row_l>>4)*2 + c2)*64 + q2*16 + (row_l&15))*8 + j2 ] = f2bf(v);
      }
    }
  }
  __syncthreads();

  load_b<2>(pe2, 0, lane, Bf);
  zero_acc(acc);
  mfma_tile<2>(A2, Bf, acc, wave, lane);
  #pragma unroll
  for (int mg=0;mg<4;mg++)
    #pragma unroll
    for (int r=0;r<4;r++){
      int row = n0 + wave*64 + mg*16 + q*4 + r;
      #pragma unroll
      for (int ng=0;ng<4;ng++){
        int col = ng*16 + ml;
        hout[(size_t)row*64 + col] = tanhf(acc[mg][ng][r] + be2[col]);
      }
    }
}

// ================= t = h @ W_gat (4 heads) + s_src/s_dst row dots =================
__global__ __launch_bounds__(128) void k_t(
    const float* __restrict__ h, const u16* __restrict__ pg,
    const float* __restrict__ asrc, const float* __restrict__ adst,
    u16* __restrict__ tall, float* __restrict__ ssrc, float* __restrict__ sdst)
{
  __shared__ short8 A[1024];
  const int tid = threadIdx.x;
  const int n0  = blockIdx.x * 128;
  for (int it=0; it<8; ++it){
    int slot = it*128 + tid;
    int row = slot >> 3, jc = slot & 7;
    const float* s = h + (size_t)(n0+row)*64 + jc*8;
    S8 w;
    #pragma unroll
    for (int j=0;j<8;j++) w.u[j] = f2bf(s[j]);
    A[((row>>4)*2 + (jc>>2))*64 + (jc&3)*16 + (row&15)] = w.v;
  }
  __syncthreads();
  const int wave = tid>>6, lane = tid&63, q = lane>>4, ml = lane&15;

  for (int chunk=0; chunk<4; ++chunk){       // chunk == head
    short8 Bf[2][4];
    load_b<2>(pg, chunk, lane, Bf);
    floatx4 acc[4][4];
    zero_acc(acc);
    mfma_tile<2>(A, Bf, acc, wave, lane);

    float as[4], ad[4];
    #pragma unroll
    for (int ng=0;ng<4;ng++){
      as[ng] = asrc[chunk*64 + ng*16 + ml];
      ad[ng] = adst[chunk*64 + ng*16 + ml];
    }
    #pragma unroll
    for (int mg=0;mg<4;mg++){
      #pragma unroll
      for (int r=0;r<4;r++){
        int row = n0 + wave*64 + mg*16 + q*4 + r;
        float ps = 0.f, pd = 0.f;
        #pragma unroll
        for (int ng=0;ng<4;ng++){
          float v = acc[mg][ng][r];
          tall[(size_t)row*256 + chunk*64 + ng*16 + ml] = f2bf(v);
          ps += v*as[ng]; pd += v*ad[ng];
        }
        #pragma unroll
        for (int s=1;s<16;s<<=1){ ps += __shfl_xor(ps, s, 64); pd += __shfl_xor(pd, s, 64); }
        if (ml == 0){ ssrc[row*4 + chunk] = ps; sdst[row*4 + chunk] = pd; }
      }
    }
  }
}

// ================= attention + aggregate + tanh(m) =================
__global__ __launch_bounds__(256) void k_attn(
    const int* __restrict__ adj, const u16* __restrict__ tall,
    const float* __restrict__ ssrc, const float* __restrict__ sdst,
    float* __restrict__ m)
{
  const int wave = threadIdx.x>>6, lane = threadIdx.x&63;
  const int nid = blockIdx.x*4 + wave;
  const int b = nid >> 14;
  const int hd = lane>>4;
  int u = adj[(size_t)nid*16 + (lane&15)];
  float sc = (u == VN) ? NEGC : (ssrc[nid*4 + hd] + sdst[((size_t)b*VN + u)*4 + hd]);
  float mx = sc;
  #pragma unroll
  for (int s=1;s<16;s<<=1) mx = fmaxf(mx, __shfl_xor(mx, s, 64));
  float ex = expf(sc - mx);
  float sm = ex;
  #pragma unroll
  for (int s=1;s<16;s<<=1) sm += __shfl_xor(sm, s, 64);
  float attn = ex / sm;

  float a0=0.f, a1=0.f, a2=0.f, a3=0.f;
  const int srcl = lane & 48;
  const uint2* tbase = (const uint2*)(tall + (size_t)b*VN*256);
  #pragma unroll
  for (int k2=0;k2<16;k2++){
    int u2 = __shfl(u, k2, 64);
    float av = __shfl(attn, srcl + k2, 64);
    if (u2 != VN){
      uint2 w = tbase[(size_t)u2*64 + lane];
      union { unsigned int u; float f; } c0,c1,c2,c3;
      c0.u = w.x << 16; c1.u = w.x & 0xffff0000u;
      c2.u = w.y << 16; c3.u = w.y & 0xffff0000u;
      a0 += av*c0.f; a1 += av*c1.f; a2 += av*c2.f; a3 += av*c3.f;
    }
  }
  a0 += __shfl_xor(a0,16,64); a0 += __shfl_xor(a0,32,64);
  a1 += __shfl_xor(a1,16,64); a1 += __shfl_xor(a1,32,64);
  a2 += __shfl_xor(a2,16,64); a2 += __shfl_xor(a2,32,64);
  a3 += __shfl_xor(a3,16,64); a3 += __shfl_xor(a3,32,64);
  if (lane < 16){
    floatx4 val;
    val[0] = tanhf(a0*0.25f); val[1] = tanhf(a1*0.25f);
    val[2] = tanhf(a2*0.25f); val[3] = tanhf(a3*0.25f);
    *(floatx4*)(m + (size_t)nid*64 + lane*4) = val;
  }
}

// ================= fused GRU =================
__global__ __launch_bounds__(128) void k_gru(
    const float* __restrict__ m, float* __restrict__ h,
    const u16* __restrict__ pzr, const u16* __restrict__ pc_,
    const float* __restrict__ bz, const float* __restrict__ br,
    const float* __restrict__ bc_)
{
  __shared__ short8 A[2048];
  const int tid = threadIdx.x;
  const int n0  = blockIdx.x * 128;
  for (int it=0; it<16; ++it){
    int slot = it*128 + tid;
    int row = slot >> 4, jc = slot & 15;
    const float* s = (jc < 8) ? (m + (size_t)(n0+row)*64 + jc*8)
                              : (h + (size_t)(n0+row)*64 + (jc-8)*8);
    S8 w;
    #pragma unroll
    for (int j=0;j<8;j++) w.u[j] = f2bf(s[j]);
    A[((row>>4)*4 + (jc>>2))*64 + (jc&3)*16 + (row&15)] = w.v;
  }
  __syncthreads();
  const int wave = tid>>6, lane = tid&63, q = lane>>4, ml = lane&15;

  short8 Bf[4][4];

  // ---- z (chunk 0) on original [m|h] ----
  floatx4 zacc[4][4];
  load_b<4>(pzr, 0, lane, Bf);
  zero_acc(zacc);
  mfma_tile<4>(A, Bf, zacc, wave, lane);

  // ---- r (chunk 1) on original [m|h] ----
  floatx4 acc[4][4];
  load_b<4>(pzr, 1, lane, Bf);
  zero_acc(acc);
  mfma_tile<4>(A, Bf, acc, wave, lane);

  // overwrite h-half of own rows with r*h; save h_old in regs
  floatx4 h_old[4][4];
  u16* As = (u16*)A;
  #pragma unroll
  for (int mg=0;mg<4;mg++){
    #pragma unroll
    for (int r=0;r<4;r++){
      int row_l = wave*64 + mg*16 + q*4 + r;
      int row   = n0 + row_l;
      #pragma unroll
      for (int ng=0;ng<4;ng++){
        int col = ng*16 + ml;
        float rv = sigm(acc[mg][ng][r] + br[col]);
        float hv = h[(size_t)row*64 + col];
        h_old[mg][ng][r] = hv;
        int kk = 64 + col;
        int c2 = kk>>5, q2 = (kk>>3)&3, j2 = kk&7;
        As[ (((row_l>>4)*4 + c2)*64 + q2*16 + (row_l&15))*8 + j2 ] = f2bf(hv*rv);
      }
    }
  }
  // no __syncthreads: each wave rewrote only its own rows' fragments and the
  // MFMA below reads only this wave's rows (lgkmcnt orders LDS ops).

  // ---- c (pc chunk 0) on [m | r*h] ----
  load_b<4>(pc_, 0, lane, Bf);
  zero_acc(acc);
  mfma_tile<4>(A, Bf, acc, wave, lane);

  #pragma unroll
  for (int mg=0;mg<4;mg++)
    #pragma unroll
    for (int r=0;r<4;r++){
      int row = n0 + wave*64 + mg*16 + q*4 + r;
      #pragma unroll
      for (int ng=0;ng<4;ng++){
        int col = ng*16 + ml;
        float zv = sigm(zacc[mg][ng][r] + bz[col]);
        float cv = tanhf(acc[mg][ng][r] + bc_[col]);
        float ho = h_old[mg][ng][r];
        h[(size_t)row*64 + col] = (1.f - zv)*ho + zv*cv;
      }
    }
}

// ================= decoder + zero-init of cost =================
__global__ __launch_bounds__(128) void k_dec(
    const float* __restrict__ h, const u16* __restrict__ pd1,
    const float* __restrict__ bd1, const float* __restrict__ Wd2, const float* __restrict__ bd2,
    float* __restrict__ nodew, float* __restrict__ cost)
{
  {
    int t = blockIdx.x*128 + threadIdx.x;
    if (t < BN) cost[t] = 0.f;
  }
  __shared__ short8 A[1024];
  const int tid = threadIdx.x;
  const int n0  = blockIdx.x * 128;
  for (int it=0; it<8; ++it){
    int slot = it*128 + tid;
    int row = slot >> 3, jc = slot & 7;
    const float* s = h + (size_t)(n0+row)*64 + jc*8;
    S8 w;
    #pragma unroll
    for (int j=0;j<8;j++) w.u[j] = f2bf(s[j]);
    A[((row>>4)*2 + (jc>>2))*64 + (jc&3)*16 + (row&15)] = w.v;
  }
  __syncthreads();
  const int wave = tid>>6, lane = tid&63, q = lane>>4, ml = lane&15;

  short8 Bf[2][4];
  load_b<2>(pd1, 0, lane, Bf);
  floatx4 acc[4][4];
  zero_acc(acc);
  mfma_tile<2>(A, Bf, acc, wave, lane);

  float wd2l[4];
  #pragma unroll
  for (int ng=0;ng<4;ng++) wd2l[ng] = Wd2[ng*16 + ml];
  float b2 = bd2[0];
  #pragma unroll
  for (int mg=0;mg<4;mg++)
    #pragma unroll
    for (int r=0;r<4;r++){
      int row = n0 + wave*64 + mg*16 + q*4 + r;
      float ps = 0.f;
      #pragma unroll
      for (int ng=0;ng<4;ng++)
        ps += tanhf(acc[mg][ng][r] + bd1[ng*16+ml]) * wd2l[ng];
      #pragma unroll
      for (int s=1;s<16;s<<=1) ps += __shfl_xor(ps, s, 64);
      if (ml == 0) nodew[row] = ps + b2;
    }
}

// ================= edge softmax + nv0 (no atomics) =================
__global__ __launch_bounds__(256) void k_pw(
    const int* __restrict__ adj, const float* __restrict__ nodew, const float* __restrict__ dem,
    float* __restrict__ normw, float* __restrict__ nv0)
{
  int e = blockIdx.x*256 + threadIdx.x;
  int node = e >> 4;
  int b = node >> 14;
  int u = adj[e];
  float pw = (u == VN) ? NEGC : nodew[(size_t)b*VN + u];
  float mx = pw;
  #pragma unroll
  for (int s=1;s<16;s<<=1) mx = fmaxf(mx, __shfl_xor(mx, s, 64));
  float ex = expf(pw - mx);
  float sm = ex;
  #pragma unroll
  for (int s=1;s<16;s<<=1) sm += __shfl_xor(sm, s, 64);
  normw[e] = ex / sm;
  if ((e & 15) == 0) nv0[node] = fmaxf(-dem[node], 0.f);
}

// ================= solver iteration: CSR gather (no atomics) =================
// 16 lanes per target node: inflow[v] = sum csr_w[i]*nv_in[csr_src[i]];
// nv_out[v] = relu(inflow - dem[v]).
__global__ __launch_bounds__(256) void k_gather(
    const u32* __restrict__ offs, const float* __restrict__ csrw, const u16* __restrict__ csrc,
    const float* __restrict__ dem, const float* __restrict__ nvin, float* __restrict__ nvout)
{
  int tid = blockIdx.x*256 + threadIdx.x;
  int g = tid >> 4;          // target slot 0..65535
  int lane = tid & 15;
  int b = g >> 14, v = g & (VN-1);
  const u32* o = offs + b*16400;
  u32 s = o[v], e = o[v+1];
  const float* w = csrw + (size_t)b*EN;
  const u16*  sc = csrc + (size_t)b*EN;
  const float* nb = nvin + (size_t)b*VN;
  float sum = 0.f;
  for (u32 i = s + (u32)lane; i < e; i += 16u)
    sum += w[i] * nb[sc[i]];
  #pragma unroll
  for (int sh=1; sh<16; sh<<=1) sum += __shfl_xor(sum, sh, 64);
  if (lane == 0) nvout[g] = fmaxf(sum - dem[g], 0.f);
}

// ================= flow materialization (+ optional cost) =================
__global__ __launch_bounds__(256) void k_flow(
    const float* __restrict__ normw, const float* __restrict__ nv,
    float* __restrict__ fout, float* __restrict__ cost)
{
  int e = blockIdx.x*256 + threadIdx.x;
  float fl = normw[e] * nv[e >> 4];
  fout[e] = fl;
  if (cost){
    float ss = fl*fl;
    #pragma unroll
    for (int sh=1; sh<64; sh<<=1) ss += __shfl_xor(ss, sh, 64);
    __shared__ float part[4];
    if ((threadIdx.x & 63) == 0) part[threadIdx.x>>6] = ss;
    __syncthreads();
    if (threadIdx.x == 0) atomicAdd(cost + (e>>18), part[0]+part[1]+part[2]+part[3]);
  }
}

// ================= launcher =================
extern "C" void kernel_launch(void* const* d_in, const int* in_sizes, int n_in,
                              void* d_out, int out_size, void* d_ws, size_t ws_size,
                              hipStream_t stream)
{
  const float* emb  = (const float*)d_in[0];
  const float* feat = (const float*)d_in[1];
  const float* dem  = (const float*)d_in[2];
  const int*   adj  = (const int*)  d_in[3];
  const float* We1 = (const float*)d_in[6];
  const float* be1 = (const float*)d_in[7];
  const float* We2 = (const float*)d_in[8];
  const float* be2 = (const float*)d_in[9];
  const float* Wg  = (const float*)d_in[10];
  const float* asrc= (const float*)d_in[11];
  const float* adst= (const float*)d_in[12];
  const float* Wz  = (const float*)d_in[13];
  const float* Uz  = (const float*)d_in[14];
  const float* bz  = (const float*)d_in[15];
  const float* Wr  = (const float*)d_in[16];
  const float* Ur  = (const float*)d_in[17];
  const float* br  = (const float*)d_in[18];
  const float* Wc  = (const float*)d_in[19];
  const float* Uc  = (const float*)d_in[20];
  const float* bc  = (const float*)d_in[21];
  const float* Wd1 = (const float*)d_in[22];
  const float* bd1 = (const float*)d_in[23];
  const float* Wd2 = (const float*)d_in[24];
  const float* bd2 = (const float*)d_in[25];

  char* ws = (char*)d_ws;
  float* h     = (float*)(ws + OFF_H);
  u16*   tall  = (u16*)  (ws + OFF_T);
  float* m     = (float*)(ws + OFF_M);
  float* ssrc  = (float*)(ws + OFF_SSRC);
  float* sdst  = (float*)(ws + OFF_SDST);
  float* nodew = (float*)(ws + OFF_NW);
  float* nv    = (float*)(ws + OFF_NV);         // [2][NN]
  u32*   cnt   = (u32*)  (ws + OFF_CNT);
  u32*   offs  = (u32*)  (ws + OFF_OFFS);
  u32*   perm  = (u32*)  (ws + OFF_PERM);
  u16*   csrc  = (u16*)  (ws + OFF_CSRC);
  float* csrw  = (float*)(ws + OFF_CSRW);
  u16* pg  = (u16*)(ws + OFF_PG);
  u16* pzr = (u16*)(ws + OFF_PZR);
  u16* pc  = (u16*)(ws + OFF_PC);
  u16* pe1 = (u16*)(ws + OFF_PE1);
  u16* pe2 = (u16*)(ws + OFF_PE2);
  u16* pd1 = (u16*)(ws + OFF_PD1);
  float* nv0b = nv;
  float* nv1b = nv + NN;

  float* out0 = (float*)d_out;            // flow   [B,V,K]  (= f10)
  float* out1 = out0 + 1048576;           // flow_cost [B]
  float* out2 = out0 + 1048580;           // norm_w [B,V,K]
  float* out3 = out0 + 2097156;           // pflow  [B,V,K]  (= f9)

  // CSR inverse adjacency build (independent of network part)
  k_csr_count<<<BN, 1024, 0, stream>>>(adj, cnt);
  k_scan     <<<BN, 1024, 0, stream>>>(cnt, offs);
  k_csr_place<<<BN, 1024, 0, stream>>>(adj, offs, perm, csrc);

  k_pack<<<208, 256, 0, stream>>>(Wg, Wz, Uz, Wr, Ur, Wc, Uc, We1, We2, Wd1,
                                  pg, pzr, pc, pe1, pe2, pd1);
  k_enc<<<512, 128, 0, stream>>>(emb, feat, pe1, pe2, be1, be2, h);

  for (int l=0; l<2; ++l){
    k_t   <<<512, 128, 0, stream>>>(h, pg, asrc, adst, tall, ssrc, sdst);
    k_attn<<<16384, 256, 0, stream>>>(adj, tall, ssrc, sdst, m);
    k_gru <<<512, 128, 0, stream>>>(m, h, pzr, pc, bz, br, bc);
  }

  k_dec<<<512, 128, 0, stream>>>(h, pd1, bd1, Wd2, bd2, nodew, out1);
  k_pw <<<4096, 256, 0, stream>>>(adj, nodew, dem, out2, nv0b);
  k_reorder<<<4096, 256, 0, stream>>>(perm, offs, out2, csrw);

  // 10 gather iterations on node vectors (ping-pong nv0b/nv1b)
  for (int i=1; i<=10; ++i){
    float* in  = (i & 1) ? nv0b : nv1b;
    float* out = (i & 1) ? nv1b : nv0b;
    k_gather<<<4096, 256, 0, stream>>>(offs, csrw, csrc, dem, in, out);
  }
  // pflow = normw * nv9 (nv9 is in nv1b), flow = normw * nv10 (nv0b) + cost
  k_flow<<<4096, 256, 0, stream>>>(out2, nv1b, out3, nullptr);
  k_flow<<<4096, 256, 0, stream>>>(out2, nv0b, out0, out1);
}

// Round 4
// 637.004 us; speedup vs baseline: 1.5695x; 1.4123x over previous
//
#include <hip/hip_runtime.h>
#include <stdint.h>
#include <math.h>

// Problem constants
#define BN 4
#define VN 16384
#define KN 16
#define HN 4
#define NN (BN*VN)          // 65536 nodes total
#define EN (VN*KN)          // 262144 edges per batch
#define NEGC (-1.0e9f)

typedef __attribute__((ext_vector_type(8))) short short8;
typedef __attribute__((ext_vector_type(4))) float floatx4;
typedef unsigned short u16;
typedef unsigned int u32;

// ---------- workspace layout (bytes) ----------
#define OFF_H      0ull                     // h       fp32 [NN][64]   16 MB
#define OFF_T      16777216ull              // t_all   bf16 [NN][256]  32 MB
#define OFF_M      50331648ull              // m       fp32 [NN][64]   16 MB
#define OFF_SSRC   67108864ull              // s_src   fp32 [NN][4]     1 MB
#define OFF_SDST   68157440ull              // s_dst   fp32 [NN][4]     1 MB
#define OFF_NW     69206016ull              // node_w  fp32 [NN]      256 KB
#define OFF_NV     69468160ull              // nv      fp32 [2][NN]   512 KB
#define OFF_CNT    69992448ull              // cnt/cur u32  [B][VN+1] pad 262400 B
#define OFF_OFFS   70254848ull              // offs    u32  [B][16400] 262400 B
#define OFF_PERM   70517248ull              // csr perm u32 [B][EN]     4 MB
#define OFF_CSRC   74711552ull              // csr src  u16 [B][EN]     2 MB
#define OFF_CSRW   76808704ull              // csr w    f32 [B][EN]     4 MB
#define OFF_PG     81003008ull              // packed W_gat   32 KB
#define OFF_PZR    (OFF_PG  + 32768ull)     // packed Wz|Wr/Uz|Ur 32 KB
#define OFF_PC     (OFF_PZR + 32768ull)     // packed Wc/Uc   16 KB
#define OFF_PE1    (OFF_PC  + 16384ull)     // packed W_enc1 (K padded to 64) 8 KB
#define OFF_PE2    (OFF_PE1 + 8192ull)      // packed W_enc2  8 KB
#define OFF_PD1    (OFF_PE2 + 8192ull)      // packed W_dec1  8 KB
// total ws use ~81.1 MB

__device__ __forceinline__ u16 f2bf(float x){
  union { float f; unsigned int u; } c; c.f = x;
  unsigned int r = c.u + 0x7fffu + ((c.u >> 16) & 1u);
  return (u16)(r >> 16);
}
__device__ __forceinline__ float bf2f(u16 s){
  union { unsigned int u; float f; } c; c.u = ((unsigned int)s) << 16;
  return c.f;
}
__device__ __forceinline__ float sigm(float x){ return 1.0f/(1.0f+expf(-x)); }

union S8 { short8 v; u16 u[8]; };

// ================= CSR inverse-adjacency build (wide, global atomics) =================
__global__ __launch_bounds__(256) void k_zero(u32* __restrict__ cnt)
{
  int i = blockIdx.x*256 + threadIdx.x;
  if (i < BN*(VN+1)) cnt[i] = 0u;
}

// pass 1: wide histogram of targets (1M random u32 atomics, L2-resident table)
__global__ __launch_bounds__(256) void k_csr_count(const int* __restrict__ adj, u32* __restrict__ cnt)
{
  int i = blockIdx.x*256 + threadIdx.x;     // 0..BN*EN-1
  int b = i >> 18;
  int t = adj[i];
  if (t < VN) atomicAdd(&cnt[b*(VN+1)+t], 1u);
}

// pass 2: exclusive prefix over v (one block per batch); also re-init cnt as cursors
__global__ __launch_bounds__(1024) void k_scan(u32* __restrict__ cnt, u32* __restrict__ offs)
{
  __shared__ u32 part[1024];
  const int b = blockIdx.x, t = threadIdx.x;
  u32* c = cnt + b*(VN+1);
  u32 loc[16];
  u32 s = 0u;
  #pragma unroll
  for (int j=0;j<16;j++){ loc[j]=s; s += c[t*16+j]; }
  part[t]=s; __syncthreads();
  for (int d=1; d<1024; d<<=1){
    u32 v = (t>=d)? part[t-d] : 0u;
    __syncthreads();
    part[t]+=v;
    __syncthreads();
  }
  u32 base = (t>0)? part[t-1] : 0u;
  u32* o = offs + b*16400;
  #pragma unroll
  for (int j=0;j<16;j++){
    o[t*16+j] = base + loc[j];
    c[t*16+j] = base + loc[j];      // cursor init (reuse cnt buffer)
  }
  if (t==1023) o[VN] = part[1023];
}

// pass 3: wide placement via global atomic cursors (order within segment irrelevant)
__global__ __launch_bounds__(256) void k_csr_place(
    const int* __restrict__ adj, u32* __restrict__ cur,
    u32* __restrict__ perm, u16* __restrict__ csrc)
{
  int i = blockIdx.x*256 + threadIdx.x;     // 0..BN*EN-1
  int b = i >> 18;
  int t = adj[i];
  if (t < VN){
    u32 pos = atomicAdd(&cur[b*(VN+1)+t], 1u);
    perm[(size_t)b*EN + pos] = (u32)(i & (EN-1));
    csrc[(size_t)b*EN + pos] = (u16)((i & (EN-1)) >> 4);
  }
}

// pass 4 (after normw known): csr_w[i] = normw[perm[i]]
__global__ __launch_bounds__(256) void k_reorder(
    const u32* __restrict__ perm, const u32* __restrict__ offs,
    const float* __restrict__ normw, float* __restrict__ csrw)
{
  int i = blockIdx.x*256 + threadIdx.x;   // 0..4*EN-1
  int b = i >> 18;
  u32 tot = offs[b*16400 + VN];
  u32 loc = (u32)(i & (EN-1));
  if (loc < tot) csrw[i] = normw[(size_t)b*EN + perm[i]];
}

// ================= weight pack kernel =================
__global__ __launch_bounds__(256) void k_pack(
    const float* __restrict__ Wg,  const float* __restrict__ Wz, const float* __restrict__ Uz,
    const float* __restrict__ Wr,  const float* __restrict__ Ur, const float* __restrict__ Wc,
    const float* __restrict__ Uc,  const float* __restrict__ We1, const float* __restrict__ We2,
    const float* __restrict__ Wd1,
    u16* __restrict__ pg, u16* __restrict__ pzr, u16* __restrict__ pc,
    u16* __restrict__ pe1, u16* __restrict__ pe2, u16* __restrict__ pd1)
{
  int e = blockIdx.x*256 + threadIdx.x;   // 0 .. 53247
  int el; u16* dst; int CN; int region;
  if      (e < 16384){ el = e;        dst = pg;  CN = 2; region = 0; }
  else if (e < 32768){ el = e-16384;  dst = pzr; CN = 4; region = 1; }
  else if (e < 40960){ el = e-32768;  dst = pc;  CN = 4; region = 2; }
  else if (e < 45056){ el = e-40960;  dst = pe1; CN = 2; region = 3; }
  else if (e < 49152){ el = e-45056;  dst = pe2; CN = 2; region = 4; }
  else               { el = e-49152;  dst = pd1; CN = 2; region = 5; }
  int j    = el & 7;
  int lane = (el >> 3) & 63;
  int rest = el >> 9;
  int c  = rest % CN;
  int ng = rest / CN;
  int k  = c*32 + (lane>>4)*8 + j;
  int n  = ng*16 + (lane&15);
  float val = 0.0f;
  if (region == 0){                 // W_gat [H][64][64], n = hd*64+d
    val = Wg[(size_t)(n>>6)*4096 + k*64 + (n&63)];
  } else if (region == 1){          // [m|h] @ [[Wz Wr],[Uz Ur]]
    if (n < 64) val = (k<64) ? Wz[k*64+n]      : Uz[(k-64)*64+n];
    else        val = (k<64) ? Wr[k*64+(n-64)] : Ur[(k-64)*64+(n-64)];
  } else if (region == 2){          // [m|r*h] @ [[Wc],[Uc]]
    val = (k<64) ? Wc[k*64+n] : Uc[(k-64)*64+n];
  } else if (region == 3){          // W_enc1 [34][64], K padded to 64 with zeros
    val = (k<34) ? We1[k*64+n] : 0.0f;
  } else if (region == 4){
    val = We2[k*64+n];
  } else {
    val = Wd1[k*64+n];
  }
  dst[el] = f2bf(val);
}

// ================= shared GEMM helpers =================
template<int CN>
__device__ __forceinline__ void load_b(const u16* p, int chunk, int lane, short8 Bf[CN][4]){
  const short8* P = (const short8*)p;
  #pragma unroll
  for (int c=0;c<CN;c++)
    #pragma unroll
    for (int ng=0; ng<4; ng++)
      Bf[c][ng] = P[((chunk*4+ng)*CN + c)*64 + lane];
}

template<int CN>
__device__ __forceinline__ void mfma_tile(const short8* A, const short8 Bf[CN][4],
                                          floatx4 acc[4][4], int wave, int lane){
  #pragma unroll
  for (int c=0;c<CN;c++){
    #pragma unroll
    for (int mg=0;mg<4;mg++){
      short8 a = A[((wave*4+mg)*CN + c)*64 + lane];
      #pragma unroll
      for (int ng=0;ng<4;ng++)
        acc[mg][ng] = __builtin_amdgcn_mfma_f32_16x16x32_bf16(a, Bf[c][ng], acc[mg][ng], 0, 0, 0);
    }
  }
}

__device__ __forceinline__ void zero_acc(floatx4 acc[4][4]){
  #pragma unroll
  for (int mg=0;mg<4;mg++)
    #pragma unroll
    for (int ng=0;ng<4;ng++){
      floatx4 z = {0.f,0.f,0.f,0.f};
      acc[mg][ng] = z;
    }
}

// ================= encoder =================
__global__ __launch_bounds__(128) void k_enc(
    const float* __restrict__ emb, const float* __restrict__ feat,
    const u16* __restrict__ pe1, const u16* __restrict__ pe2,
    const float* __restrict__ be1, const float* __restrict__ be2,
    float* __restrict__ hout)
{
  __shared__ short8 A1[1024];
  __shared__ short8 A2[1024];
  const int tid = threadIdx.x;
  const int n0  = blockIdx.x * 128;
  for (int it=0; it<8; ++it){
    int slot = it*128 + tid;
    int row = slot >> 3, jc = slot & 7;
    S8 w;
    if (jc < 4){
      const float* s = emb + (size_t)(n0+row)*32 + jc*8;
      #pragma unroll
      for (int j=0;j<8;j++) w.u[j] = f2bf(s[j]);
    } else if (jc == 4){
      const float* s = feat + (size_t)(n0+row)*2;
      w.u[0] = f2bf(s[0]); w.u[1] = f2bf(s[1]);
      #pragma unroll
      for (int j=2;j<8;j++) w.u[j] = 0;
    } else {
      #pragma unroll
      for (int j=0;j<8;j++) w.u[j] = 0;
    }
    A1[((row>>4)*2 + (jc>>2))*64 + (jc&3)*16 + (row&15)] = w.v;
  }
  __syncthreads();
  const int wave = tid>>6, lane = tid&63, q = lane>>4, ml = lane&15;

  short8 Bf[2][4];
  load_b<2>(pe1, 0, lane, Bf);
  floatx4 acc[4][4];
  zero_acc(acc);
  mfma_tile<2>(A1, Bf, acc, wave, lane);

  u16* A2s = (u16*)A2;
  #pragma unroll
  for (int mg=0;mg<4;mg++){
    #pragma unroll
    for (int r=0;r<4;r++){
      int row_l = wave*64 + mg*16 + q*4 + r;
      #pragma unroll
      for (int ng=0;ng<4;ng++){
        int k2 = ng*16 + ml;
        float v = tanhf(acc[mg][ng][r] + be1[k2]);
        int c2 = k2>>5, q2=(k2>>3)&3, j2=k2&7;
        A2s[ (((row_l>>4)*2 + c2)*64 + q2*16 + (row_l&15))*8 + j2 ] = f2bf(v);
      }
    }
  }
  __syncthreads();

  load_b<2>(pe2, 0, lane, Bf);
  zero_acc(acc);
  mfma_tile<2>(A2, Bf, acc, wave, lane);
  #pragma unroll
  for (int mg=0;mg<4;mg++)
    #pragma unroll
    for (int r=0;r<4;r++){
      int row = n0 + wave*64 + mg*16 + q*4 + r;
      #pragma unroll
      for (int ng=0;ng<4;ng++){
        int col = ng*16 + ml;
        hout[(size_t)row*64 + col] = tanhf(acc[mg][ng][r] + be2[col]);
      }
    }
}

// ================= t = h @ W_gat (4 heads) + s_src/s_dst row dots =================
__global__ __launch_bounds__(128) void k_t(
    const float* __restrict__ h, const u16* __restrict__ pg,
    const float* __restrict__ asrc, const float* __restrict__ adst,
    u16* __restrict__ tall, float* __restrict__ ssrc, float* __restrict__ sdst)
{
  __shared__ short8 A[1024];
  const int tid = threadIdx.x;
  const int n0  = blockIdx.x * 128;
  for (int it=0; it<8; ++it){
    int slot = it*128 + tid;
    int row = slot >> 3, jc = slot & 7;
    const float* s = h + (size_t)(n0+row)*64 + jc*8;
    S8 w;
    #pragma unroll
    for (int j=0;j<8;j++) w.u[j] = f2bf(s[j]);
    A[((row>>4)*2 + (jc>>2))*64 + (jc&3)*16 + (row&15)] = w.v;
  }
  __syncthreads();
  const int wave = tid>>6, lane = tid&63, q = lane>>4, ml = lane&15;

  for (int chunk=0; chunk<4; ++chunk){       // chunk == head
    short8 Bf[2][4];
    load_b<2>(pg, chunk, lane, Bf);
    floatx4 acc[4][4];
    zero_acc(acc);
    mfma_tile<2>(A, Bf, acc, wave, lane);

    float as[4], ad[4];
    #pragma unroll
    for (int ng=0;ng<4;ng++){
      as[ng] = asrc[chunk*64 + ng*16 + ml];
      ad[ng] = adst[chunk*64 + ng*16 + ml];
    }
    #pragma unroll
    for (int mg=0;mg<4;mg++){
      #pragma unroll
      for (int r=0;r<4;r++){
        int row = n0 + wave*64 + mg*16 + q*4 + r;
        float ps = 0.f, pd = 0.f;
        #pragma unroll
        for (int ng=0;ng<4;ng++){
          float v = acc[mg][ng][r];
          tall[(size_t)row*256 + chunk*64 + ng*16 + ml] = f2bf(v);
          ps += v*as[ng]; pd += v*ad[ng];
        }
        #pragma unroll
        for (int s=1;s<16;s<<=1){ ps += __shfl_xor(ps, s, 64); pd += __shfl_xor(pd, s, 64); }
        if (ml == 0){ ssrc[row*4 + chunk] = ps; sdst[row*4 + chunk] = pd; }
      }
    }
  }
}

// ================= attention + aggregate + tanh(m) =================
__global__ __launch_bounds__(256) void k_attn(
    const int* __restrict__ adj, const u16* __restrict__ tall,
    const float* __restrict__ ssrc, const float* __restrict__ sdst,
    float* __restrict__ m)
{
  const int wave = threadIdx.x>>6, lane = threadIdx.x&63;
  const int nid = blockIdx.x*4 + wave;
  const int b = nid >> 14;
  const int hd = lane>>4;
  int u = adj[(size_t)nid*16 + (lane&15)];
  float sc = (u == VN) ? NEGC : (ssrc[nid*4 + hd] + sdst[((size_t)b*VN + u)*4 + hd]);
  float mx = sc;
  #pragma unroll
  for (int s=1;s<16;s<<=1) mx = fmaxf(mx, __shfl_xor(mx, s, 64));
  float ex = expf(sc - mx);
  float sm = ex;
  #pragma unroll
  for (int s=1;s<16;s<<=1) sm += __shfl_xor(sm, s, 64);
  float attn = ex / sm;

  float a0=0.f, a1=0.f, a2=0.f, a3=0.f;
  const int srcl = lane & 48;
  const uint2* tbase = (const uint2*)(tall + (size_t)b*VN*256);
  #pragma unroll
  for (int k2=0;k2<16;k2++){
    int u2 = __shfl(u, k2, 64);
    float av = __shfl(attn, srcl + k2, 64);
    if (u2 != VN){
      uint2 w = tbase[(size_t)u2*64 + lane];
      union { unsigned int u; float f; } c0,c1,c2,c3;
      c0.u = w.x << 16; c1.u = w.x & 0xffff0000u;
      c2.u = w.y << 16; c3.u = w.y & 0xffff0000u;
      a0 += av*c0.f; a1 += av*c1.f; a2 += av*c2.f; a3 += av*c3.f;
    }
  }
  a0 += __shfl_xor(a0,16,64); a0 += __shfl_xor(a0,32,64);
  a1 += __shfl_xor(a1,16,64); a1 += __shfl_xor(a1,32,64);
  a2 += __shfl_xor(a2,16,64); a2 += __shfl_xor(a2,32,64);
  a3 += __shfl_xor(a3,16,64); a3 += __shfl_xor(a3,32,64);
  if (lane < 16){
    floatx4 val;
    val[0] = tanhf(a0*0.25f); val[1] = tanhf(a1*0.25f);
    val[2] = tanhf(a2*0.25f); val[3] = tanhf(a3*0.25f);
    *(floatx4*)(m + (size_t)nid*64 + lane*4) = val;
  }
}

// ================= fused GRU =================
__global__ __launch_bounds__(128) void k_gru(
    const float* __restrict__ m, float* __restrict__ h,
    const u16* __restrict__ pzr, const u16* __restrict__ pc_,
    const float* __restrict__ bz, const float* __restrict__ br,
    const float* __restrict__ bc_)
{
  __shared__ short8 A[2048];
  const int tid = threadIdx.x;
  const int n0  = blockIdx.x * 128;
  for (int it=0; it<16; ++it){
    int slot = it*128 + tid;
    int row = slot >> 4, jc = slot & 15;
    const float* s = (jc < 8) ? (m + (size_t)(n0+row)*64 + jc*8)
                              : (h + (size_t)(n0+row)*64 + (jc-8)*8);
    S8 w;
    #pragma unroll
    for (int j=0;j<8;j++) w.u[j] = f2bf(s[j]);
    A[((row>>4)*4 + (jc>>2))*64 + (jc&3)*16 + (row&15)] = w.v;
  }
  __syncthreads();
  const int wave = tid>>6, lane = tid&63, q = lane>>4, ml = lane&15;

  short8 Bf[4][4];

  // ---- z (chunk 0) on original [m|h] ----
  floatx4 zacc[4][4];
  load_b<4>(pzr, 0, lane, Bf);
  zero_acc(zacc);
  mfma_tile<4>(A, Bf, zacc, wave, lane);

  // ---- r (chunk 1) on original [m|h] ----
  floatx4 acc[4][4];
  load_b<4>(pzr, 1, lane, Bf);
  zero_acc(acc);
  mfma_tile<4>(A, Bf, acc, wave, lane);

  // overwrite h-half of own rows with r*h; save h_old in regs
  floatx4 h_old[4][4];
  u16* As = (u16*)A;
  #pragma unroll
  for (int mg=0;mg<4;mg++){
    #pragma unroll
    for (int r=0;r<4;r++){
      int row_l = wave*64 + mg*16 + q*4 + r;
      int row   = n0 + row_l;
      #pragma unroll
      for (int ng=0;ng<4;ng++){
        int col = ng*16 + ml;
        float rv = sigm(acc[mg][ng][r] + br[col]);
        float hv = h[(size_t)row*64 + col];
        h_old[mg][ng][r] = hv;
        int kk = 64 + col;
        int c2 = kk>>5, q2 = (kk>>3)&3, j2 = kk&7;
        As[ (((row_l>>4)*4 + c2)*64 + q2*16 + (row_l&15))*8 + j2 ] = f2bf(hv*rv);
      }
    }
  }
  // no __syncthreads: each wave rewrote only its own rows' fragments and the
  // MFMA below reads only this wave's rows (lgkmcnt orders LDS ops).

  // ---- c (pc chunk 0) on [m | r*h] ----
  load_b<4>(pc_, 0, lane, Bf);
  zero_acc(acc);
  mfma_tile<4>(A, Bf, acc, wave, lane);

  #pragma unroll
  for (int mg=0;mg<4;mg++)
    #pragma unroll
    for (int r=0;r<4;r++){
      int row = n0 + wave*64 + mg*16 + q*4 + r;
      #pragma unroll
      for (int ng=0;ng<4;ng++){
        int col = ng*16 + ml;
        float zv = sigm(zacc[mg][ng][r] + bz[col]);
        float cv = tanhf(acc[mg][ng][r] + bc_[col]);
        float ho = h_old[mg][ng][r];
        h[(size_t)row*64 + col] = (1.f - zv)*ho + zv*cv;
      }
    }
}

// ================= decoder + zero-init of cost =================
__global__ __launch_bounds__(128) void k_dec(
    const float* __restrict__ h, const u16* __restrict__ pd1,
    const float* __restrict__ bd1, const float* __restrict__ Wd2, const float* __restrict__ bd2,
    float* __restrict__ nodew, float* __restrict__ cost)
{
  {
    int t = blockIdx.x*128 + threadIdx.x;
    if (t < BN) cost[t] = 0.f;
  }
  __shared__ short8 A[1024];
  const int tid = threadIdx.x;
  const int n0  = blockIdx.x * 128;
  for (int it=0; it<8; ++it){
    int slot = it*128 + tid;
    int row = slot >> 3, jc = slot & 7;
    const float* s = h + (size_t)(n0+row)*64 + jc*8;
    S8 w;
    #pragma unroll
    for (int j=0;j<8;j++) w.u[j] = f2bf(s[j]);
    A[((row>>4)*2 + (jc>>2))*64 + (jc&3)*16 + (row&15)] = w.v;
  }
  __syncthreads();
  const int wave = tid>>6, lane = tid&63, q = lane>>4, ml = lane&15;

  short8 Bf[2][4];
  load_b<2>(pd1, 0, lane, Bf);
  floatx4 acc[4][4];
  zero_acc(acc);
  mfma_tile<2>(A, Bf, acc, wave, lane);

  float wd2l[4];
  #pragma unroll
  for (int ng=0;ng<4;ng++) wd2l[ng] = Wd2[ng*16 + ml];
  float b2 = bd2[0];
  #pragma unroll
  for (int mg=0;mg<4;mg++)
    #pragma unroll
    for (int r=0;r<4;r++){
      int row = n0 + wave*64 + mg*16 + q*4 + r;
      float ps = 0.f;
      #pragma unroll
      for (int ng=0;ng<4;ng++)
        ps += tanhf(acc[mg][ng][r] + bd1[ng*16+ml]) * wd2l[ng];
      #pragma unroll
      for (int s=1;s<16;s<<=1) ps += __shfl_xor(ps, s, 64);
      if (ml == 0) nodew[row] = ps + b2;
    }
}

// ================= edge softmax + nv0 (no atomics) =================
__global__ __launch_bounds__(256) void k_pw(
    const int* __restrict__ adj, const float* __restrict__ nodew, const float* __restrict__ dem,
    float* __restrict__ normw, float* __restrict__ nv0)
{
  int e = blockIdx.x*256 + threadIdx.x;
  int node = e >> 4;
  int b = node >> 14;
  int u = adj[e];
  float pw = (u == VN) ? NEGC : nodew[(size_t)b*VN + u];
  float mx = pw;
  #pragma unroll
  for (int s=1;s<16;s<<=1) mx = fmaxf(mx, __shfl_xor(mx, s, 64));
  float ex = expf(pw - mx);
  float sm = ex;
  #pragma unroll
  for (int s=1;s<16;s<<=1) sm += __shfl_xor(sm, s, 64);
  normw[e] = ex / sm;
  if ((e & 15) == 0) nv0[node] = fmaxf(-dem[node], 0.f);
}

// ================= solver iteration: CSR gather (no atomics) =================
__global__ __launch_bounds__(256) void k_gather(
    const u32* __restrict__ offs, const float* __restrict__ csrw, const u16* __restrict__ csrc,
    const float* __restrict__ dem, const float* __restrict__ nvin, float* __restrict__ nvout)
{
  int tid = blockIdx.x*256 + threadIdx.x;
  int g = tid >> 4;          // target slot 0..65535
  int lane = tid & 15;
  int b = g >> 14, v = g & (VN-1);
  const u32* o = offs + b*16400;
  u32 s = o[v], e = o[v+1];
  const float* w = csrw + (size_t)b*EN;
  const u16*  sc = csrc + (size_t)b*EN;
  const float* nb = nvin + (size_t)b*VN;
  float sum = 0.f;
  for (u32 i = s + (u32)lane; i < e; i += 16u)
    sum += w[i] * nb[sc[i]];
  #pragma unroll
  for (int sh=1; sh<16; sh<<=1) sum += __shfl_xor(sum, sh, 64);
  if (lane == 0) nvout[g] = fmaxf(sum - dem[g], 0.f);
}

// ================= flow materialization (+ optional cost) =================
__global__ __launch_bounds__(256) void k_flow(
    const float* __restrict__ normw, const float* __restrict__ nv,
    float* __restrict__ fout, float* __restrict__ cost)
{
  int e = blockIdx.x*256 + threadIdx.x;
  float fl = normw[e] * nv[e >> 4];
  fout[e] = fl;
  if (cost){
    float ss = fl*fl;
    #pragma unroll
    for (int sh=1; sh<64; sh<<=1) ss += __shfl_xor(ss, sh, 64);
    __shared__ float part[4];
    if ((threadIdx.x & 63) == 0) part[threadIdx.x>>6] = ss;
    __syncthreads();
    if (threadIdx.x == 0) atomicAdd(cost + (e>>18), part[0]+part[1]+part[2]+part[3]);
  }
}

// ================= launcher =================
extern "C" void kernel_launch(void* const* d_in, const int* in_sizes, int n_in,
                              void* d_out, int out_size, void* d_ws, size_t ws_size,
                              hipStream_t stream)
{
  const float* emb  = (const float*)d_in[0];
  const float* feat = (const float*)d_in[1];
  const float* dem  = (const float*)d_in[2];
  const int*   adj  = (const int*)  d_in[3];
  const float* We1 = (const float*)d_in[6];
  const float* be1 = (const float*)d_in[7];
  const float* We2 = (const float*)d_in[8];
  const float* be2 = (const float*)d_in[9];
  const float* Wg  = (const float*)d_in[10];
  const float* asrc= (const float*)d_in[11];
  const float* adst= (const float*)d_in[12];
  const float* Wz  = (const float*)d_in[13];
  const float* Uz  = (const float*)d_in[14];
  const float* bz  = (const float*)d_in[15];
  const float* Wr  = (const float*)d_in[16];
  const float* Ur  = (const float*)d_in[17];
  const float* br  = (const float*)d_in[18];
  const float* Wc  = (const float*)d_in[19];
  const float* Uc  = (const float*)d_in[20];
  const float* bc  = (const float*)d_in[21];
  const float* Wd1 = (const float*)d_in[22];
  const float* bd1 = (const float*)d_in[23];
  const float* Wd2 = (const float*)d_in[24];
  const float* bd2 = (const float*)d_in[25];

  char* ws = (char*)d_ws;
  float* h     = (float*)(ws + OFF_H);
  u16*   tall  = (u16*)  (ws + OFF_T);
  float* m     = (float*)(ws + OFF_M);
  float* ssrc  = (float*)(ws + OFF_SSRC);
  float* sdst  = (float*)(ws + OFF_SDST);
  float* nodew = (float*)(ws + OFF_NW);
  float* nv    = (float*)(ws + OFF_NV);         // [2][NN]
  u32*   cnt   = (u32*)  (ws + OFF_CNT);        // doubles as cursors after k_scan
  u32*   offs  = (u32*)  (ws + OFF_OFFS);
  u32*   perm  = (u32*)  (ws + OFF_PERM);
  u16*   csrc  = (u16*)  (ws + OFF_CSRC);
  float* csrw  = (float*)(ws + OFF_CSRW);
  u16* pg  = (u16*)(ws + OFF_PG);
  u16* pzr = (u16*)(ws + OFF_PZR);
  u16* pc  = (u16*)(ws + OFF_PC);
  u16* pe1 = (u16*)(ws + OFF_PE1);
  u16* pe2 = (u16*)(ws + OFF_PE2);
  u16* pd1 = (u16*)(ws + OFF_PD1);
  float* nv0b = nv;
  float* nv1b = nv + NN;

  float* out0 = (float*)d_out;            // flow   [B,V,K]  (= f10)
  float* out1 = out0 + 1048576;           // flow_cost [B]
  float* out2 = out0 + 1048580;           // norm_w [B,V,K]
  float* out3 = out0 + 2097156;           // pflow  [B,V,K]  (= f9)

  // CSR inverse adjacency build (wide, global atomics; order-free)
  k_zero     <<<257, 256, 0, stream>>>(cnt);
  k_csr_count<<<4096, 256, 0, stream>>>(adj, cnt);
  k_scan     <<<BN, 1024, 0, stream>>>(cnt, offs);
  k_csr_place<<<4096, 256, 0, stream>>>(adj, cnt, perm, csrc);

  k_pack<<<208, 256, 0, stream>>>(Wg, Wz, Uz, Wr, Ur, Wc, Uc, We1, We2, Wd1,
                                  pg, pzr, pc, pe1, pe2, pd1);
  k_enc<<<512, 128, 0, stream>>>(emb, feat, pe1, pe2, be1, be2, h);

  for (int l=0; l<2; ++l){
    k_t   <<<512, 128, 0, stream>>>(h, pg, asrc, adst, tall, ssrc, sdst);
    k_attn<<<16384, 256, 0, stream>>>(adj, tall, ssrc, sdst, m);
    k_gru <<<512, 128, 0, stream>>>(m, h, pzr, pc, bz, br, bc);
  }

  k_dec<<<512, 128, 0, stream>>>(h, pd1, bd1, Wd2, bd2, nodew, out1);
  k_pw <<<4096, 256, 0, stream>>>(adj, nodew, dem, out2, nv0b);
  k_reorder<<<4096, 256, 0, stream>>>(perm, offs, out2, csrw);

  // 10 gather iterations on node vectors (ping-pong nv0b/nv1b)
  for (int i=1; i<=10; ++i){
    float* in  = (i & 1) ? nv0b : nv1b;
    float* out = (i & 1) ? nv1b : nv0b;
    k_gather<<<4096, 256, 0, stream>>>(offs, csrw, csrc, dem, in, out);
  }
  // pflow = normw * nv9 (nv1b), flow = normw * nv10 (nv0b) + cost
  k_flow<<<4096, 256, 0, stream>>>(out2, nv1b, out3, nullptr);
  k_flow<<<4096, 256, 0, stream>>>(out2, nv0b, out0, out1);
}

// Round 5
// 569.267 us; speedup vs baseline: 1.7563x; 1.1190x over previous
//
#include <hip/hip_runtime.h>
#include <stdint.h>
#include <math.h>

// Problem constants
#define BN 4
#define VN 16384
#define KN 16
#define HN 4
#define NN (BN*VN)          // 65536 nodes total
#define EN (VN*KN)          // 262144 edges per batch
#define CAP 64              // inverse-adjacency bucket capacity (P(deg>64) ~ 1e-13)
#define NEGC (-1.0e9f)

typedef __attribute__((ext_vector_type(8))) short short8;
typedef __attribute__((ext_vector_type(4))) float floatx4;
typedef unsigned short u16;
typedef unsigned int u32;

// ---------- workspace layout (bytes) ----------
#define OFF_H      0ull                     // h       fp32 [NN][64]   16 MB
#define OFF_T      16777216ull              // t_all   bf16 [NN][256]  32 MB; REUSED as bucket uint2[NN][64] by k_pw onward
#define OFF_M      50331648ull              // m       fp32 [NN][64]   16 MB
#define OFF_SSRC   67108864ull              // s_src   fp32 [NN][4]     1 MB
#define OFF_SDST   68157440ull              // s_dst   fp32 [NN][4]     1 MB
#define OFF_NW     69206016ull              // node_w  fp32 [NN]      256 KB
#define OFF_NV     69468160ull              // nv      fp32 [2][NN]   512 KB
#define OFF_CNT    69992448ull              // cnt     u32  [NN]      256 KB
#define OFF_PG     70254848ull              // packed W_gat   32 KB
#define OFF_PZR    (OFF_PG  + 32768ull)     // packed Wz|Wr/Uz|Ur 32 KB
#define OFF_PC     (OFF_PZR + 32768ull)     // packed Wc/Uc   16 KB
#define OFF_PE1    (OFF_PC  + 16384ull)     // packed W_enc1 (K padded to 64) 8 KB
#define OFF_PE2    (OFF_PE1 + 8192ull)      // packed W_enc2  8 KB
#define OFF_PD1    (OFF_PE2 + 8192ull)      // packed W_dec1  8 KB
// total ws use ~70.4 MB

__device__ __forceinline__ u16 f2bf(float x){
  union { float f; unsigned int u; } c; c.f = x;
  unsigned int r = c.u + 0x7fffu + ((c.u >> 16) & 1u);
  return (u16)(r >> 16);
}
__device__ __forceinline__ float bf2f(u16 s){
  union { unsigned int u; float f; } c; c.u = ((unsigned int)s) << 16;
  return c.f;
}
__device__ __forceinline__ float sigm(float x){ return 1.0f/(1.0f+expf(-x)); }

union S8 { short8 v; u16 u[8]; };
union FU { float f; u32 u; };

// ================= zero the bucket counters =================
__global__ __launch_bounds__(256) void k_zero(u32* __restrict__ cnt)
{
  cnt[blockIdx.x*256 + threadIdx.x] = 0u;
}

// ================= weight pack kernel =================
// packed layout: flat elem e = ((ng*CN + c)*64 + lane)*8 + j holds Mat[k][n],
// k = c*32 + (lane>>4)*8 + j,  n = ng*16 + (lane&15),  CN = K/32.
__global__ __launch_bounds__(256) void k_pack(
    const float* __restrict__ Wg,  const float* __restrict__ Wz, const float* __restrict__ Uz,
    const float* __restrict__ Wr,  const float* __restrict__ Ur, const float* __restrict__ Wc,
    const float* __restrict__ Uc,  const float* __restrict__ We1, const float* __restrict__ We2,
    const float* __restrict__ Wd1,
    u16* __restrict__ pg, u16* __restrict__ pzr, u16* __restrict__ pc,
    u16* __restrict__ pe1, u16* __restrict__ pe2, u16* __restrict__ pd1)
{
  int e = blockIdx.x*256 + threadIdx.x;   // 0 .. 53247
  int el; u16* dst; int CN; int region;
  if      (e < 16384){ el = e;        dst = pg;  CN = 2; region = 0; }
  else if (e < 32768){ el = e-16384;  dst = pzr; CN = 4; region = 1; }
  else if (e < 40960){ el = e-32768;  dst = pc;  CN = 4; region = 2; }
  else if (e < 45056){ el = e-40960;  dst = pe1; CN = 2; region = 3; }
  else if (e < 49152){ el = e-45056;  dst = pe2; CN = 2; region = 4; }
  else               { el = e-49152;  dst = pd1; CN = 2; region = 5; }
  int j    = el & 7;
  int lane = (el >> 3) & 63;
  int rest = el >> 9;
  int c  = rest % CN;
  int ng = rest / CN;
  int k  = c*32 + (lane>>4)*8 + j;
  int n  = ng*16 + (lane&15);
  float val = 0.0f;
  if (region == 0){                 // W_gat [H][64][64], n = hd*64+d
    val = Wg[(size_t)(n>>6)*4096 + k*64 + (n&63)];
  } else if (region == 1){          // [m|h] @ [[Wz Wr],[Uz Ur]]
    if (n < 64) val = (k<64) ? Wz[k*64+n]      : Uz[(k-64)*64+n];
    else        val = (k<64) ? Wr[k*64+(n-64)] : Ur[(k-64)*64+(n-64)];
  } else if (region == 2){          // [m|r*h] @ [[Wc],[Uc]]
    val = (k<64) ? Wc[k*64+n] : Uc[(k-64)*64+n];
  } else if (region == 3){          // W_enc1 [34][64], K padded to 64 with zeros
    val = (k<34) ? We1[k*64+n] : 0.0f;
  } else if (region == 4){
    val = We2[k*64+n];
  } else {
    val = Wd1[k*64+n];
  }
  dst[el] = f2bf(val);
}

// ================= shared GEMM helpers =================
template<int CN>
__device__ __forceinline__ void load_b(const u16* p, int chunk, int lane, short8 Bf[CN][4]){
  const short8* P = (const short8*)p;
  #pragma unroll
  for (int c=0;c<CN;c++)
    #pragma unroll
    for (int ng=0; ng<4; ng++)
      Bf[c][ng] = P[((chunk*4+ng)*CN + c)*64 + lane];
}

template<int CN>
__device__ __forceinline__ void mfma_tile(const short8* A, const short8 Bf[CN][4],
                                          floatx4 acc[4][4], int wave, int lane){
  #pragma unroll
  for (int c=0;c<CN;c++){
    #pragma unroll
    for (int mg=0;mg<4;mg++){
      short8 a = A[((wave*4+mg)*CN + c)*64 + lane];
      #pragma unroll
      for (int ng=0;ng<4;ng++)
        acc[mg][ng] = __builtin_amdgcn_mfma_f32_16x16x32_bf16(a, Bf[c][ng], acc[mg][ng], 0, 0, 0);
    }
  }
}

__device__ __forceinline__ void zero_acc(floatx4 acc[4][4]){
  #pragma unroll
  for (int mg=0;mg<4;mg++)
    #pragma unroll
    for (int ng=0;ng<4;ng++){
      floatx4 z = {0.f,0.f,0.f,0.f};
      acc[mg][ng] = z;
    }
}

// ================= encoder =================
__global__ __launch_bounds__(128) void k_enc(
    const float* __restrict__ emb, const float* __restrict__ feat,
    const u16* __restrict__ pe1, const u16* __restrict__ pe2,
    const float* __restrict__ be1, const float* __restrict__ be2,
    float* __restrict__ hout)
{
  __shared__ short8 A1[1024];
  __shared__ short8 A2[1024];
  const int tid = threadIdx.x;
  const int n0  = blockIdx.x * 128;
  for (int it=0; it<8; ++it){
    int slot = it*128 + tid;
    int row = slot >> 3, jc = slot & 7;
    S8 w;
    if (jc < 4){
      const float* s = emb + (size_t)(n0+row)*32 + jc*8;
      #pragma unroll
      for (int j=0;j<8;j++) w.u[j] = f2bf(s[j]);
    } else if (jc == 4){
      const float* s = feat + (size_t)(n0+row)*2;
      w.u[0] = f2bf(s[0]); w.u[1] = f2bf(s[1]);
      #pragma unroll
      for (int j=2;j<8;j++) w.u[j] = 0;
    } else {
      #pragma unroll
      for (int j=0;j<8;j++) w.u[j] = 0;
    }
    A1[((row>>4)*2 + (jc>>2))*64 + (jc&3)*16 + (row&15)] = w.v;
  }
  __syncthreads();
  const int wave = tid>>6, lane = tid&63, q = lane>>4, ml = lane&15;

  short8 Bf[2][4];
  load_b<2>(pe1, 0, lane, Bf);
  floatx4 acc[4][4];
  zero_acc(acc);
  mfma_tile<2>(A1, Bf, acc, wave, lane);

  u16* A2s = (u16*)A2;
  #pragma unroll
  for (int mg=0;mg<4;mg++){
    #pragma unroll
    for (int r=0;r<4;r++){
      int row_l = wave*64 + mg*16 + q*4 + r;
      #pragma unroll
      for (int ng=0;ng<4;ng++){
        int k2 = ng*16 + ml;
        float v = tanhf(acc[mg][ng][r] + be1[k2]);
        int c2 = k2>>5, q2=(k2>>3)&3, j2=k2&7;
        A2s[ (((row_l>>4)*2 + c2)*64 + q2*16 + (row_l&15))*8 + j2 ] = f2bf(v);
      }
    }
  }
  __syncthreads();

  load_b<2>(pe2, 0, lane, Bf);
  zero_acc(acc);
  mfma_tile<2>(A2, Bf, acc, wave, lane);
  #pragma unroll
  for (int mg=0;mg<4;mg++)
    #pragma unroll
    for (int r=0;r<4;r++){
      int row = n0 + wave*64 + mg*16 + q*4 + r;
      #pragma unroll
      for (int ng=0;ng<4;ng++){
        int col = ng*16 + ml;
        hout[(size_t)row*64 + col] = tanhf(acc[mg][ng][r] + be2[col]);
      }
    }
}

// ================= t = h @ W_gat (4 heads) + s_src/s_dst row dots =================
__global__ __launch_bounds__(128) void k_t(
    const float* __restrict__ h, const u16* __restrict__ pg,
    const float* __restrict__ asrc, const float* __restrict__ adst,
    u16* __restrict__ tall, float* __restrict__ ssrc, float* __restrict__ sdst)
{
  __shared__ short8 A[1024];
  const int tid = threadIdx.x;
  const int n0  = blockIdx.x * 128;
  for (int it=0; it<8; ++it){
    int slot = it*128 + tid;
    int row = slot >> 3, jc = slot & 7;
    const float* s = h + (size_t)(n0+row)*64 + jc*8;
    S8 w;
    #pragma unroll
    for (int j=0;j<8;j++) w.u[j] = f2bf(s[j]);
    A[((row>>4)*2 + (jc>>2))*64 + (jc&3)*16 + (row&15)] = w.v;
  }
  __syncthreads();
  const int wave = tid>>6, lane = tid&63, q = lane>>4, ml = lane&15;

  for (int chunk=0; chunk<4; ++chunk){       // chunk == head
    short8 Bf[2][4];
    load_b<2>(pg, chunk, lane, Bf);
    floatx4 acc[4][4];
    zero_acc(acc);
    mfma_tile<2>(A, Bf, acc, wave, lane);

    float as[4], ad[4];
    #pragma unroll
    for (int ng=0;ng<4;ng++){
      as[ng] = asrc[chunk*64 + ng*16 + ml];
      ad[ng] = adst[chunk*64 + ng*16 + ml];
    }
    #pragma unroll
    for (int mg=0;mg<4;mg++){
      #pragma unroll
      for (int r=0;r<4;r++){
        int row = n0 + wave*64 + mg*16 + q*4 + r;
        float ps = 0.f, pd = 0.f;
        #pragma unroll
        for (int ng=0;ng<4;ng++){
          float v = acc[mg][ng][r];
          tall[(size_t)row*256 + chunk*64 + ng*16 + ml] = f2bf(v);
          ps += v*as[ng]; pd += v*ad[ng];
        }
        #pragma unroll
        for (int s=1;s<16;s<<=1){ ps += __shfl_xor(ps, s, 64); pd += __shfl_xor(pd, s, 64); }
        if (ml == 0){ ssrc[row*4 + chunk] = ps; sdst[row*4 + chunk] = pd; }
      }
    }
  }
}

// ================= attention + aggregate + tanh(m) =================
__global__ __launch_bounds__(256) void k_attn(
    const int* __restrict__ adj, const u16* __restrict__ tall,
    const float* __restrict__ ssrc, const float* __restrict__ sdst,
    float* __restrict__ m)
{
  const int wave = threadIdx.x>>6, lane = threadIdx.x&63;
  const int nid = blockIdx.x*4 + wave;
  const int b = nid >> 14;
  const int hd = lane>>4;
  int u = adj[(size_t)nid*16 + (lane&15)];
  float sc = (u == VN) ? NEGC : (ssrc[nid*4 + hd] + sdst[((size_t)b*VN + u)*4 + hd]);
  float mx = sc;
  #pragma unroll
  for (int s=1;s<16;s<<=1) mx = fmaxf(mx, __shfl_xor(mx, s, 64));
  float ex = expf(sc - mx);
  float sm = ex;
  #pragma unroll
  for (int s=1;s<16;s<<=1) sm += __shfl_xor(sm, s, 64);
  float attn = ex / sm;

  float a0=0.f, a1=0.f, a2=0.f, a3=0.f;
  const int srcl = lane & 48;
  const uint2* tbase = (const uint2*)(tall + (size_t)b*VN*256);
  #pragma unroll
  for (int k2=0;k2<16;k2++){
    int u2 = __shfl(u, k2, 64);
    float av = __shfl(attn, srcl + k2, 64);
    if (u2 != VN){
      uint2 w = tbase[(size_t)u2*64 + lane];
      union { unsigned int u; float f; } c0,c1,c2,c3;
      c0.u = w.x << 16; c1.u = w.x & 0xffff0000u;
      c2.u = w.y << 16; c3.u = w.y & 0xffff0000u;
      a0 += av*c0.f; a1 += av*c1.f; a2 += av*c2.f; a3 += av*c3.f;
    }
  }
  a0 += __shfl_xor(a0,16,64); a0 += __shfl_xor(a0,32,64);
  a1 += __shfl_xor(a1,16,64); a1 += __shfl_xor(a1,32,64);
  a2 += __shfl_xor(a2,16,64); a2 += __shfl_xor(a2,32,64);
  a3 += __shfl_xor(a3,16,64); a3 += __shfl_xor(a3,32,64);
  if (lane < 16){
    floatx4 val;
    val[0] = tanhf(a0*0.25f); val[1] = tanhf(a1*0.25f);
    val[2] = tanhf(a2*0.25f); val[3] = tanhf(a3*0.25f);
    *(floatx4*)(m + (size_t)nid*64 + lane*4) = val;
  }
}

// ================= fused GRU =================
__global__ __launch_bounds__(128) void k_gru(
    const float* __restrict__ m, float* __restrict__ h,
    const u16* __restrict__ pzr, const u16* __restrict__ pc_,
    const float* __restrict__ bz, const float* __restrict__ br,
    const float* __restrict__ bc_)
{
  __shared__ short8 A[2048];
  const int tid = threadIdx.x;
  const int n0  = blockIdx.x * 128;
  for (int it=0; it<16; ++it){
    int slot = it*128 + tid;
    int row = slot >> 4, jc = slot & 15;
    const float* s = (jc < 8) ? (m + (size_t)(n0+row)*64 + jc*8)
                              : (h + (size_t)(n0+row)*64 + (jc-8)*8);
    S8 w;
    #pragma unroll
    for (int j=0;j<8;j++) w.u[j] = f2bf(s[j]);
    A[((row>>4)*4 + (jc>>2))*64 + (jc&3)*16 + (row&15)] = w.v;
  }
  __syncthreads();
  const int wave = tid>>6, lane = tid&63, q = lane>>4, ml = lane&15;

  short8 Bf[4][4];

  // ---- z (chunk 0) on original [m|h] ----
  floatx4 zacc[4][4];
  load_b<4>(pzr, 0, lane, Bf);
  zero_acc(zacc);
  mfma_tile<4>(A, Bf, zacc, wave, lane);

  // ---- r (chunk 1) on original [m|h] ----
  floatx4 acc[4][4];
  load_b<4>(pzr, 1, lane, Bf);
  zero_acc(acc);
  mfma_tile<4>(A, Bf, acc, wave, lane);

  // overwrite h-half of own rows with r*h; save h_old in regs
  floatx4 h_old[4][4];
  u16* As = (u16*)A;
  #pragma unroll
  for (int mg=0;mg<4;mg++){
    #pragma unroll
    for (int r=0;r<4;r++){
      int row_l = wave*64 + mg*16 + q*4 + r;
      int row   = n0 + row_l;
      #pragma unroll
      for (int ng=0;ng<4;ng++){
        int col = ng*16 + ml;
        float rv = sigm(acc[mg][ng][r] + br[col]);
        float hv = h[(size_t)row*64 + col];
        h_old[mg][ng][r] = hv;
        int kk = 64 + col;
        int c2 = kk>>5, q2 = (kk>>3)&3, j2 = kk&7;
        As[ (((row_l>>4)*4 + c2)*64 + q2*16 + (row_l&15))*8 + j2 ] = f2bf(hv*rv);
      }
    }
  }
  // no __syncthreads: each wave rewrote only its own rows' fragments and the
  // MFMA below reads only this wave's rows (lgkmcnt orders LDS ops).

  // ---- c (pc chunk 0) on [m | r*h] ----
  load_b<4>(pc_, 0, lane, Bf);
  zero_acc(acc);
  mfma_tile<4>(A, Bf, acc, wave, lane);

  #pragma unroll
  for (int mg=0;mg<4;mg++)
    #pragma unroll
    for (int r=0;r<4;r++){
      int row = n0 + wave*64 + mg*16 + q*4 + r;
      #pragma unroll
      for (int ng=0;ng<4;ng++){
        int col = ng*16 + ml;
        float zv = sigm(zacc[mg][ng][r] + bz[col]);
        float cv = tanhf(acc[mg][ng][r] + bc_[col]);
        float ho = h_old[mg][ng][r];
        h[(size_t)row*64 + col] = (1.f - zv)*ho + zv*cv;
      }
    }
}

// ================= decoder + zero-init of cost =================
__global__ __launch_bounds__(128) void k_dec(
    const float* __restrict__ h, const u16* __restrict__ pd1,
    const float* __restrict__ bd1, const float* __restrict__ Wd2, const float* __restrict__ bd2,
    float* __restrict__ nodew, float* __restrict__ cost)
{
  {
    int t = blockIdx.x*128 + threadIdx.x;
    if (t < BN) cost[t] = 0.f;
  }
  __shared__ short8 A[1024];
  const int tid = threadIdx.x;
  const int n0  = blockIdx.x * 128;
  for (int it=0; it<8; ++it){
    int slot = it*128 + tid;
    int row = slot >> 3, jc = slot & 7;
    const float* s = h + (size_t)(n0+row)*64 + jc*8;
    S8 w;
    #pragma unroll
    for (int j=0;j<8;j++) w.u[j] = f2bf(s[j]);
    A[((row>>4)*2 + (jc>>2))*64 + (jc&3)*16 + (row&15)] = w.v;
  }
  __syncthreads();
  const int wave = tid>>6, lane = tid&63, q = lane>>4, ml = lane&15;

  short8 Bf[2][4];
  load_b<2>(pd1, 0, lane, Bf);
  floatx4 acc[4][4];
  zero_acc(acc);
  mfma_tile<2>(A, Bf, acc, wave, lane);

  float wd2l[4];
  #pragma unroll
  for (int ng=0;ng<4;ng++) wd2l[ng] = Wd2[ng*16 + ml];
  float b2 = bd2[0];
  #pragma unroll
  for (int mg=0;mg<4;mg++)
    #pragma unroll
    for (int r=0;r<4;r++){
      int row = n0 + wave*64 + mg*16 + q*4 + r;
      float ps = 0.f;
      #pragma unroll
      for (int ng=0;ng<4;ng++)
        ps += tanhf(acc[mg][ng][r] + bd1[ng*16+ml]) * wd2l[ng];
      #pragma unroll
      for (int s=1;s<16;s<<=1) ps += __shfl_xor(ps, s, 64);
      if (ml == 0) nodew[row] = ps + b2;
    }
}

// ===== edge softmax + nv0 + INLINE inverse-adjacency bucket build =====
// bucket[(b*VN+u)*CAP + pos] = { bits(norm_w), src_node_v }; cnt counts per target.
__global__ __launch_bounds__(256) void k_pw(
    const int* __restrict__ adj, const float* __restrict__ nodew, const float* __restrict__ dem,
    float* __restrict__ normw, float* __restrict__ nv0,
    u32* __restrict__ cnt, uint2* __restrict__ bucket)
{
  int e = blockIdx.x*256 + threadIdx.x;
  int node = e >> 4;
  int b = node >> 14;
  int u = adj[e];
  float pw = (u == VN) ? NEGC : nodew[(size_t)b*VN + u];
  float mx = pw;
  #pragma unroll
  for (int s=1;s<16;s<<=1) mx = fmaxf(mx, __shfl_xor(mx, s, 64));
  float ex = expf(pw - mx);
  float sm = ex;
  #pragma unroll
  for (int s=1;s<16;s<<=1) sm += __shfl_xor(sm, s, 64);
  float nw = ex / sm;
  normw[e] = nw;
  if ((e & 15) == 0) nv0[node] = fmaxf(-dem[node], 0.f);
  if (u < VN){
    int g = b*VN + u;
    u32 pos = atomicAdd(&cnt[g], 1u);
    if (pos < CAP){
      FU fu; fu.f = nw;
      uint2 rec; rec.x = fu.u; rec.y = (u32)(node & (VN-1));
      bucket[(size_t)g*CAP + pos] = rec;
    }
  }
}

// ================= solver iteration: bucket gather (no atomics) =================
__global__ __launch_bounds__(256) void k_gather(
    const u32* __restrict__ cnt, const uint2* __restrict__ bucket,
    const float* __restrict__ dem, const float* __restrict__ nvin, float* __restrict__ nvout)
{
  int tid = blockIdx.x*256 + threadIdx.x;
  int g = tid >> 4;          // target slot 0..65535
  int lane = tid & 15;
  int b = g >> 14;
  u32 n = cnt[g];
  if (n > CAP) n = CAP;
  const uint2* bk = bucket + (size_t)g*CAP;
  const float* nb = nvin + (size_t)b*VN;
  float sum = 0.f;
  for (u32 i = (u32)lane; i < n; i += 16u){
    uint2 r = bk[i];
    FU fu; fu.u = r.x;
    sum += fu.f * nb[r.y];
  }
  #pragma unroll
  for (int sh=1; sh<16; sh<<=1) sum += __shfl_xor(sum, sh, 64);
  if (lane == 0) nvout[g] = fmaxf(sum - dem[g], 0.f);
}

// ================= flow materialization (+ optional cost) =================
__global__ __launch_bounds__(256) void k_flow(
    const float* __restrict__ normw, const float* __restrict__ nv,
    float* __restrict__ fout, float* __restrict__ cost)
{
  int e = blockIdx.x*256 + threadIdx.x;
  float fl = normw[e] * nv[e >> 4];
  fout[e] = fl;
  if (cost){
    float ss = fl*fl;
    #pragma unroll
    for (int sh=1; sh<64; sh<<=1) ss += __shfl_xor(ss, sh, 64);
    __shared__ float part[4];
    if ((threadIdx.x & 63) == 0) part[threadIdx.x>>6] = ss;
    __syncthreads();
    if (threadIdx.x == 0) atomicAdd(cost + (e>>18), part[0]+part[1]+part[2]+part[3]);
  }
}

// ================= launcher =================
extern "C" void kernel_launch(void* const* d_in, const int* in_sizes, int n_in,
                              void* d_out, int out_size, void* d_ws, size_t ws_size,
                              hipStream_t stream)
{
  const float* emb  = (const float*)d_in[0];
  const float* feat = (const float*)d_in[1];
  const float* dem  = (const float*)d_in[2];
  const int*   adj  = (const int*)  d_in[3];
  const float* We1 = (const float*)d_in[6];
  const float* be1 = (const float*)d_in[7];
  const float* We2 = (const float*)d_in[8];
  const float* be2 = (const float*)d_in[9];
  const float* Wg  = (const float*)d_in[10];
  const float* asrc= (const float*)d_in[11];
  const float* adst= (const float*)d_in[12];
  const float* Wz  = (const float*)d_in[13];
  const float* Uz  = (const float*)d_in[14];
  const float* bz  = (const float*)d_in[15];
  const float* Wr  = (const float*)d_in[16];
  const float* Ur  = (const float*)d_in[17];
  const float* br  = (const float*)d_in[18];
  const float* Wc  = (const float*)d_in[19];
  const float* Uc  = (const float*)d_in[20];
  const float* bc  = (const float*)d_in[21];
  const float* Wd1 = (const float*)d_in[22];
  const float* bd1 = (const float*)d_in[23];
  const float* Wd2 = (const float*)d_in[24];
  const float* bd2 = (const float*)d_in[25];

  char* ws = (char*)d_ws;
  float* h     = (float*)(ws + OFF_H);
  u16*   tall  = (u16*)  (ws + OFF_T);
  uint2* bucket= (uint2*)(ws + OFF_T);          // reuses tall region after attn done
  float* m     = (float*)(ws + OFF_M);
  float* ssrc  = (float*)(ws + OFF_SSRC);
  float* sdst  = (float*)(ws + OFF_SDST);
  float* nodew = (float*)(ws + OFF_NW);
  float* nv    = (float*)(ws + OFF_NV);         // [2][NN]
  u32*   cnt   = (u32*)  (ws + OFF_CNT);
  u16* pg  = (u16*)(ws + OFF_PG);
  u16* pzr = (u16*)(ws + OFF_PZR);
  u16* pc  = (u16*)(ws + OFF_PC);
  u16* pe1 = (u16*)(ws + OFF_PE1);
  u16* pe2 = (u16*)(ws + OFF_PE2);
  u16* pd1 = (u16*)(ws + OFF_PD1);
  float* nv0b = nv;
  float* nv1b = nv + NN;

  float* out0 = (float*)d_out;            // flow   [B,V,K]  (= f10)
  float* out1 = out0 + 1048576;           // flow_cost [B]
  float* out2 = out0 + 1048580;           // norm_w [B,V,K]
  float* out3 = out0 + 2097156;           // pflow  [B,V,K]  (= f9)

  k_zero<<<256, 256, 0, stream>>>(cnt);
  k_pack<<<208, 256, 0, stream>>>(Wg, Wz, Uz, Wr, Ur, Wc, Uc, We1, We2, Wd1,
                                  pg, pzr, pc, pe1, pe2, pd1);
  k_enc<<<512, 128, 0, stream>>>(emb, feat, pe1, pe2, be1, be2, h);

  for (int l=0; l<2; ++l){
    k_t   <<<512, 128, 0, stream>>>(h, pg, asrc, adst, tall, ssrc, sdst);
    k_attn<<<16384, 256, 0, stream>>>(adj, tall, ssrc, sdst, m);
    k_gru <<<512, 128, 0, stream>>>(m, h, pzr, pc, bz, br, bc);
  }

  k_dec<<<512, 128, 0, stream>>>(h, pd1, bd1, Wd2, bd2, nodew, out1);
  // k_pw overwrites the tall region as the inverse-adjacency bucket (tall is dead now)
  k_pw <<<4096, 256, 0, stream>>>(adj, nodew, dem, out2, nv0b, cnt, bucket);

  // 10 gather iterations on node vectors (ping-pong nv0b/nv1b)
  for (int i=1; i<=10; ++i){
    float* in  = (i & 1) ? nv0b : nv1b;
    float* out = (i & 1) ? nv1b : nv0b;
    k_gather<<<4096, 256, 0, stream>>>(cnt, bucket, dem, in, out);
  }
  // pflow = normw * nv9 (nv1b), flow = normw * nv10 (nv0b) + cost
  k_flow<<<4096, 256, 0, stream>>>(out2, nv1b, out3, nullptr);
  k_flow<<<4096, 256, 0, stream>>>(out2, nv0b, out0, out1);
}

// Round 6
// 500.429 us; speedup vs baseline: 1.9979x; 1.1376x over previous
//
#include <hip/hip_runtime.h>
#include <stdint.h>
#include <math.h>

// Problem constants
#define BN 4
#define VN 16384
#define KN 16
#define HN 4
#define NN (BN*VN)          // 65536 nodes total
#define EN (VN*KN)          // 262144 edges per batch
#define CAP 64              // inverse-adjacency bucket capacity (P(deg>64) ~ 1e-13)
#define NEGC (-1.0e9f)

typedef __attribute__((ext_vector_type(8))) short short8;
typedef __attribute__((ext_vector_type(4))) float floatx4;
typedef __attribute__((ext_vector_type(2))) float floatx2;
typedef unsigned short u16;
typedef unsigned int u32;

// ---------- workspace layout (bytes) ----------
// t_all is now fp8: u32[NN+1][64] = 16.8 MB (1 spare row for branchless masked reads).
// The 32 MB bucket overlays the same region (t dead by the time k_pw runs).
#define OFF_H      0ull                     // h       fp32 [NN][64]   16 MB
#define OFF_T      16777216ull              // t_all   fp8  [NN+1][256] 16.8 MB; REUSED as bucket uint2[NN][64] (32 MB)
#define OFF_M      50331648ull              // m       fp32 [NN][64]   16 MB (PERMUTED dim order, see pack)
#define OFF_SSRC   67108864ull              // s_src   fp32 [NN][4]     1 MB
#define OFF_SDST   68157440ull              // s_dst   fp32 [NN][4]     1 MB
#define OFF_NW     69206016ull              // node_w  fp32 [NN]      256 KB
#define OFF_NV     69468160ull              // nv      fp32 [2][NN]   512 KB
#define OFF_CNT    69992448ull              // cnt     u32  [NN]      256 KB
#define OFF_PG     70254848ull              // packed W_gat   32 KB
#define OFF_PZR    (OFF_PG  + 32768ull)     // packed Wz|Wr/Uz|Ur 32 KB
#define OFF_PC     (OFF_PZR + 32768ull)     // packed Wc/Uc   16 KB
#define OFF_PE1    (OFF_PC  + 16384ull)     // packed W_enc1 (K padded to 64) 8 KB
#define OFF_PE2    (OFF_PE1 + 8192ull)      // packed W_enc2  8 KB
#define OFF_PD1    (OFF_PE2 + 8192ull)      // packed W_dec1  8 KB
// total ws use ~70.4 MB

__device__ __forceinline__ u16 f2bf(float x){
  union { float f; unsigned int u; } c; c.f = x;
  unsigned int r = c.u + 0x7fffu + ((c.u >> 16) & 1u);
  return (u16)(r >> 16);
}
__device__ __forceinline__ float bf2f(u16 s){
  union { unsigned int u; float f; } c; c.u = ((unsigned int)s) << 16;
  return c.f;
}
__device__ __forceinline__ float sigm(float x){ return 1.0f/(1.0f+expf(-x)); }

union S8 { short8 v; u16 u[8]; };
union FU { float f; u32 u; };

// ================= zero the bucket counters =================
__global__ __launch_bounds__(256) void k_zero(u32* __restrict__ cnt)
{
  cnt[blockIdx.x*256 + threadIdx.x] = 0u;
}

// ================= weight pack kernel =================
// packed layout: flat elem e = ((ng*CN + c)*64 + lane)*8 + j holds Mat[k][n],
// k = c*32 + (lane>>4)*8 + j,  n = ng*16 + (lane&15),  CN = K/32.
// m is stored PERMUTED by k_attn: m_perm[p] = m_std[(p&3)*16 + (p>>2)].
// Compensate: for the m-half rows (k<64) of pzr/pc use source row (k&3)*16+(k>>2).
__global__ __launch_bounds__(256) void k_pack(
    const float* __restrict__ Wg,  const float* __restrict__ Wz, const float* __restrict__ Uz,
    const float* __restrict__ Wr,  const float* __restrict__ Ur, const float* __restrict__ Wc,
    const float* __restrict__ Uc,  const float* __restrict__ We1, const float* __restrict__ We2,
    const float* __restrict__ Wd1,
    u16* __restrict__ pg, u16* __restrict__ pzr, u16* __restrict__ pc,
    u16* __restrict__ pe1, u16* __restrict__ pe2, u16* __restrict__ pd1)
{
  int e = blockIdx.x*256 + threadIdx.x;   // 0 .. 53247
  int el; u16* dst; int CN; int region;
  if      (e < 16384){ el = e;        dst = pg;  CN = 2; region = 0; }
  else if (e < 32768){ el = e-16384;  dst = pzr; CN = 4; region = 1; }
  else if (e < 40960){ el = e-32768;  dst = pc;  CN = 4; region = 2; }
  else if (e < 45056){ el = e-40960;  dst = pe1; CN = 2; region = 3; }
  else if (e < 49152){ el = e-45056;  dst = pe2; CN = 2; region = 4; }
  else               { el = e-49152;  dst = pd1; CN = 2; region = 5; }
  int j    = el & 7;
  int lane = (el >> 3) & 63;
  int rest = el >> 9;
  int c  = rest % CN;
  int ng = rest / CN;
  int k  = c*32 + (lane>>4)*8 + j;
  int n  = ng*16 + (lane&15);
  float val = 0.0f;
  if (region == 0){                 // W_gat [H][64][64], n = hd*64+d
    val = Wg[(size_t)(n>>6)*4096 + k*64 + (n&63)];
  } else if (region == 1){          // [m_perm|h] @ [[Wz Wr],[Uz Ur]]
    int km = (k&3)*16 + ((k>>2)&15);              // un-permute m row
    if (n < 64) val = (k<64) ? Wz[km*64+n]      : Uz[(k-64)*64+n];
    else        val = (k<64) ? Wr[km*64+(n-64)] : Ur[(k-64)*64+(n-64)];
  } else if (region == 2){          // [m_perm|r*h] @ [[Wc],[Uc]]
    int km = (k&3)*16 + ((k>>2)&15);
    val = (k<64) ? Wc[km*64+n] : Uc[(k-64)*64+n];
  } else if (region == 3){          // W_enc1 [34][64], K padded to 64 with zeros
    val = (k<34) ? We1[k*64+n] : 0.0f;
  } else if (region == 4){
    val = We2[k*64+n];
  } else {
    val = Wd1[k*64+n];
  }
  dst[el] = f2bf(val);
}

// ================= shared GEMM helpers =================
template<int CN>
__device__ __forceinline__ void load_b(const u16* p, int chunk, int lane, short8 Bf[CN][4]){
  const short8* P = (const short8*)p;
  #pragma unroll
  for (int c=0;c<CN;c++)
    #pragma unroll
    for (int ng=0; ng<4; ng++)
      Bf[c][ng] = P[((chunk*4+ng)*CN + c)*64 + lane];
}

template<int CN>
__device__ __forceinline__ void mfma_tile(const short8* A, const short8 Bf[CN][4],
                                          floatx4 acc[4][4], int wave, int lane){
  #pragma unroll
  for (int c=0;c<CN;c++){
    #pragma unroll
    for (int mg=0;mg<4;mg++){
      short8 a = A[((wave*4+mg)*CN + c)*64 + lane];
      #pragma unroll
      for (int ng=0;ng<4;ng++)
        acc[mg][ng] = __builtin_amdgcn_mfma_f32_16x16x32_bf16(a, Bf[c][ng], acc[mg][ng], 0, 0, 0);
    }
  }
}

__device__ __forceinline__ void zero_acc(floatx4 acc[4][4]){
  #pragma unroll
  for (int mg=0;mg<4;mg++)
    #pragma unroll
    for (int ng=0;ng<4;ng++){
      floatx4 z = {0.f,0.f,0.f,0.f};
      acc[mg][ng] = z;
    }
}

// ================= encoder =================
__global__ __launch_bounds__(128) void k_enc(
    const float* __restrict__ emb, const float* __restrict__ feat,
    const u16* __restrict__ pe1, const u16* __restrict__ pe2,
    const float* __restrict__ be1, const float* __restrict__ be2,
    float* __restrict__ hout)
{
  __shared__ short8 A1[1024];
  __shared__ short8 A2[1024];
  const int tid = threadIdx.x;
  const int n0  = blockIdx.x * 128;
  for (int it=0; it<8; ++it){
    int slot = it*128 + tid;
    int row = slot >> 3, jc = slot & 7;
    S8 w;
    if (jc < 4){
      const float* s = emb + (size_t)(n0+row)*32 + jc*8;
      #pragma unroll
      for (int j=0;j<8;j++) w.u[j] = f2bf(s[j]);
    } else if (jc == 4){
      const float* s = feat + (size_t)(n0+row)*2;
      w.u[0] = f2bf(s[0]); w.u[1] = f2bf(s[1]);
      #pragma unroll
      for (int j=2;j<8;j++) w.u[j] = 0;
    } else {
      #pragma unroll
      for (int j=0;j<8;j++) w.u[j] = 0;
    }
    A1[((row>>4)*2 + (jc>>2))*64 + (jc&3)*16 + (row&15)] = w.v;
  }
  __syncthreads();
  const int wave = tid>>6, lane = tid&63, q = lane>>4, ml = lane&15;

  short8 Bf[2][4];
  load_b<2>(pe1, 0, lane, Bf);
  floatx4 acc[4][4];
  zero_acc(acc);
  mfma_tile<2>(A1, Bf, acc, wave, lane);

  u16* A2s = (u16*)A2;
  #pragma unroll
  for (int mg=0;mg<4;mg++){
    #pragma unroll
    for (int r=0;r<4;r++){
      int row_l = wave*64 + mg*16 + q*4 + r;
      #pragma unroll
      for (int ng=0;ng<4;ng++){
        int k2 = ng*16 + ml;
        float v = tanhf(acc[mg][ng][r] + be1[k2]);
        int c2 = k2>>5, q2=(k2>>3)&3, j2=k2&7;
        A2s[ (((row_l>>4)*2 + c2)*64 + q2*16 + (row_l&15))*8 + j2 ] = f2bf(v);
      }
    }
  }
  __syncthreads();

  load_b<2>(pe2, 0, lane, Bf);
  zero_acc(acc);
  mfma_tile<2>(A2, Bf, acc, wave, lane);
  #pragma unroll
  for (int mg=0;mg<4;mg++)
    #pragma unroll
    for (int r=0;r<4;r++){
      int row = n0 + wave*64 + mg*16 + q*4 + r;
      #pragma unroll
      for (int ng=0;ng<4;ng++){
        int col = ng*16 + ml;
        hout[(size_t)row*64 + col] = tanhf(acc[mg][ng][r] + be2[col]);
      }
    }
}

// ===== t = h @ W_gat (4 heads) -> fp8 rows (permuted layout) + s_src/s_dst dots =====
// t row layout (256 bytes): byte position chunk*64 + ml*4 + ng holds t[head=chunk][col=ng*16+ml].
// Each lane packs its 4 accumulator values into ONE u32 store.
__global__ __launch_bounds__(128) void k_t(
    const float* __restrict__ h, const u16* __restrict__ pg,
    const float* __restrict__ asrc, const float* __restrict__ adst,
    u32* __restrict__ tq, float* __restrict__ ssrc, float* __restrict__ sdst)
{
  __shared__ short8 A[1024];
  const int tid = threadIdx.x;
  const int n0  = blockIdx.x * 128;
  for (int it=0; it<8; ++it){
    int slot = it*128 + tid;
    int row = slot >> 3, jc = slot & 7;
    const float* s = h + (size_t)(n0+row)*64 + jc*8;
    S8 w;
    #pragma unroll
    for (int j=0;j<8;j++) w.u[j] = f2bf(s[j]);
    A[((row>>4)*2 + (jc>>2))*64 + (jc&3)*16 + (row&15)] = w.v;
  }
  __syncthreads();
  const int wave = tid>>6, lane = tid&63, q = lane>>4, ml = lane&15;

  for (int chunk=0; chunk<4; ++chunk){       // chunk == head
    short8 Bf[2][4];
    load_b<2>(pg, chunk, lane, Bf);
    floatx4 acc[4][4];
    zero_acc(acc);
    mfma_tile<2>(A, Bf, acc, wave, lane);

    float as[4], ad[4];
    #pragma unroll
    for (int ng=0;ng<4;ng++){
      as[ng] = asrc[chunk*64 + ng*16 + ml];
      ad[ng] = adst[chunk*64 + ng*16 + ml];
    }
    #pragma unroll
    for (int mg=0;mg<4;mg++){
      #pragma unroll
      for (int r=0;r<4;r++){
        int row = n0 + wave*64 + mg*16 + q*4 + r;
        float v0 = acc[mg][0][r], v1 = acc[mg][1][r];
        float v2 = acc[mg][2][r], v3 = acc[mg][3][r];
        int pk = __builtin_amdgcn_cvt_pk_fp8_f32(v0, v1, 0, false);
        pk     = __builtin_amdgcn_cvt_pk_fp8_f32(v2, v3, pk, true);
        tq[(size_t)row*64 + chunk*16 + ml] = (u32)pk;
        float ps = v0*as[0] + v1*as[1] + v2*as[2] + v3*as[3];
        float pd = v0*ad[0] + v1*ad[1] + v2*ad[2] + v3*ad[3];
        #pragma unroll
        for (int s=1;s<16;s<<=1){ ps += __shfl_xor(ps, s, 64); pd += __shfl_xor(pd, s, 64); }
        if (ml == 0){ ssrc[row*4 + chunk] = ps; sdst[row*4 + chunk] = pd; }
      }
    }
  }
}

// ================= attention + aggregate + tanh(m) =================
// scores: lane = hd*16+k (full precision). gather: lane l loads ONE u32 (4 fp8) of the
// 256-B row -> head l>>4, cols j*16+(l&15). Branchless: masked neighbors have attn==0
// exactly (expf(-1e9-mx)==0), so garbage row data contributes 0. Row index <= NN (spare row).
__global__ __launch_bounds__(256) void k_attn(
    const int* __restrict__ adj, const u32* __restrict__ tq,
    const float* __restrict__ ssrc, const float* __restrict__ sdst,
    float* __restrict__ m)
{
  const int wave = threadIdx.x>>6, lane = threadIdx.x&63;
  const int nid = blockIdx.x*4 + wave;
  const int b = nid >> 14;
  const int hd = lane>>4;
  int u = adj[(size_t)nid*16 + (lane&15)];
  float sc = (u == VN) ? NEGC : (ssrc[nid*4 + hd] + sdst[((size_t)b*VN + u)*4 + hd]);
  float mx = sc;
  #pragma unroll
  for (int s=1;s<16;s<<=1) mx = fmaxf(mx, __shfl_xor(mx, s, 64));
  float ex = expf(sc - mx);
  float sm = ex;
  #pragma unroll
  for (int s=1;s<16;s<<=1) sm += __shfl_xor(sm, s, 64);
  float attn = ex / sm;

  float a0=0.f, a1=0.f, a2=0.f, a3=0.f;
  const int srcl = lane & 48;
  #pragma unroll
  for (int k2=0;k2<16;k2++){
    int u2 = __shfl(u, k2, 64);             // wave-uniform
    float av = __shfl(attn, srcl + k2, 64); // this head's weight for neighbor k2
    u32 w = tq[((size_t)b*VN + u2)*64 + lane];
    floatx2 f01 = __builtin_amdgcn_cvt_pk_f32_fp8((int)w, false);
    floatx2 f23 = __builtin_amdgcn_cvt_pk_f32_fp8((int)w, true);
    a0 += av*f01.x; a1 += av*f01.y; a2 += av*f23.x; a3 += av*f23.y;
  }
  // fold 4 head groups: lanes l, l^16, l^32, l^48
  a0 += __shfl_xor(a0,16,64); a0 += __shfl_xor(a0,32,64);
  a1 += __shfl_xor(a1,16,64); a1 += __shfl_xor(a1,32,64);
  a2 += __shfl_xor(a2,16,64); a2 += __shfl_xor(a2,32,64);
  a3 += __shfl_xor(a3,16,64); a3 += __shfl_xor(a3,32,64);
  if (lane < 16){
    // stores m in PERMUTED dim order: m[nid*64 + 4*ml + j] = agg[std col j*16+ml]
    floatx4 val;
    val[0] = tanhf(a0*0.25f); val[1] = tanhf(a1*0.25f);
    val[2] = tanhf(a2*0.25f); val[3] = tanhf(a3*0.25f);
    *(floatx4*)(m + (size_t)nid*64 + lane*4) = val;
  }
}

// ================= fused GRU =================
__global__ __launch_bounds__(128) void k_gru(
    const float* __restrict__ m, float* __restrict__ h,
    const u16* __restrict__ pzr, const u16* __restrict__ pc_,
    const float* __restrict__ bz, const float* __restrict__ br,
    const float* __restrict__ bc_)
{
  __shared__ short8 A[2048];
  const int tid = threadIdx.x;
  const int n0  = blockIdx.x * 128;
  for (int it=0; it<16; ++it){
    int slot = it*128 + tid;
    int row = slot >> 4, jc = slot & 15;
    const float* s = (jc < 8) ? (m + (size_t)(n0+row)*64 + jc*8)
                              : (h + (size_t)(n0+row)*64 + (jc-8)*8);
    S8 w;
    #pragma unroll
    for (int j=0;j<8;j++) w.u[j] = f2bf(s[j]);
    A[((row>>4)*4 + (jc>>2))*64 + (jc&3)*16 + (row&15)] = w.v;
  }
  __syncthreads();
  const int wave = tid>>6, lane = tid&63, q = lane>>4, ml = lane&15;

  short8 Bf[4][4];

  // ---- z (chunk 0) on original [m|h] ----
  floatx4 zacc[4][4];
  load_b<4>(pzr, 0, lane, Bf);
  zero_acc(zacc);
  mfma_tile<4>(A, Bf, zacc, wave, lane);

  // ---- r (chunk 1) on original [m|h] ----
  floatx4 acc[4][4];
  load_b<4>(pzr, 1, lane, Bf);
  zero_acc(acc);
  mfma_tile<4>(A, Bf, acc, wave, lane);

  // overwrite h-half of own rows with r*h; save h_old in regs
  floatx4 h_old[4][4];
  u16* As = (u16*)A;
  #pragma unroll
  for (int mg=0;mg<4;mg++){
    #pragma unroll
    for (int r=0;r<4;r++){
      int row_l = wave*64 + mg*16 + q*4 + r;
      int row   = n0 + row_l;
      #pragma unroll
      for (int ng=0;ng<4;ng++){
        int col = ng*16 + ml;
        float rv = sigm(acc[mg][ng][r] + br[col]);
        float hv = h[(size_t)row*64 + col];
        h_old[mg][ng][r] = hv;
        int kk = 64 + col;
        int c2 = kk>>5, q2 = (kk>>3)&3, j2 = kk&7;
        As[ (((row_l>>4)*4 + c2)*64 + q2*16 + (row_l&15))*8 + j2 ] = f2bf(hv*rv);
      }
    }
  }
  // no __syncthreads: each wave rewrote only its own rows' fragments and the
  // MFMA below reads only this wave's rows (lgkmcnt orders LDS ops).

  // ---- c (pc chunk 0) on [m | r*h] ----
  load_b<4>(pc_, 0, lane, Bf);
  zero_acc(acc);
  mfma_tile<4>(A, Bf, acc, wave, lane);

  #pragma unroll
  for (int mg=0;mg<4;mg++)
    #pragma unroll
    for (int r=0;r<4;r++){
      int row = n0 + wave*64 + mg*16 + q*4 + r;
      #pragma unroll
      for (int ng=0;ng<4;ng++){
        int col = ng*16 + ml;
        float zv = sigm(zacc[mg][ng][r] + bz[col]);
        float cv = tanhf(acc[mg][ng][r] + bc_[col]);
        float ho = h_old[mg][ng][r];
        h[(size_t)row*64 + col] = (1.f - zv)*ho + zv*cv;
      }
    }
}

// ================= decoder + zero-init of cost =================
__global__ __launch_bounds__(128) void k_dec(
    const float* __restrict__ h, const u16* __restrict__ pd1,
    const float* __restrict__ bd1, const float* __restrict__ Wd2, const float* __restrict__ bd2,
    float* __restrict__ nodew, float* __restrict__ cost)
{
  {
    int t = blockIdx.x*128 + threadIdx.x;
    if (t < BN) cost[t] = 0.f;
  }
  __shared__ short8 A[1024];
  const int tid = threadIdx.x;
  const int n0  = blockIdx.x * 128;
  for (int it=0; it<8; ++it){
    int slot = it*128 + tid;
    int row = slot >> 3, jc = slot & 7;
    const float* s = h + (size_t)(n0+row)*64 + jc*8;
    S8 w;
    #pragma unroll
    for (int j=0;j<8;j++) w.u[j] = f2bf(s[j]);
    A[((row>>4)*2 + (jc>>2))*64 + (jc&3)*16 + (row&15)] = w.v;
  }
  __syncthreads();
  const int wave = tid>>6, lane = tid&63, q = lane>>4, ml = lane&15;

  short8 Bf[2][4];
  load_b<2>(pd1, 0, lane, Bf);
  floatx4 acc[4][4];
  zero_acc(acc);
  mfma_tile<2>(A, Bf, acc, wave, lane);

  float wd2l[4];
  #pragma unroll
  for (int ng=0;ng<4;ng++) wd2l[ng] = Wd2[ng*16 + ml];
  float b2 = bd2[0];
  #pragma unroll
  for (int mg=0;mg<4;mg++)
    #pragma unroll
    for (int r=0;r<4;r++){
      int row = n0 + wave*64 + mg*16 + q*4 + r;
      float ps = 0.f;
      #pragma unroll
      for (int ng=0;ng<4;ng++)
        ps += tanhf(acc[mg][ng][r] + bd1[ng*16+ml]) * wd2l[ng];
      #pragma unroll
      for (int s=1;s<16;s<<=1) ps += __shfl_xor(ps, s, 64);
      if (ml == 0) nodew[row] = ps + b2;
    }
}

// ===== edge softmax + nv0 + INLINE inverse-adjacency bucket build =====
__global__ __launch_bounds__(256) void k_pw(
    const int* __restrict__ adj, const float* __restrict__ nodew, const float* __restrict__ dem,
    float* __restrict__ normw, float* __restrict__ nv0,
    u32* __restrict__ cnt, uint2* __restrict__ bucket)
{
  int e = blockIdx.x*256 + threadIdx.x;
  int node = e >> 4;
  int b = node >> 14;
  int u = adj[e];
  float pw = (u == VN) ? NEGC : nodew[(size_t)b*VN + u];
  float mx = pw;
  #pragma unroll
  for (int s=1;s<16;s<<=1) mx = fmaxf(mx, __shfl_xor(mx, s, 64));
  float ex = expf(pw - mx);
  float sm = ex;
  #pragma unroll
  for (int s=1;s<16;s<<=1) sm += __shfl_xor(sm, s, 64);
  float nw = ex / sm;
  normw[e] = nw;
  if ((e & 15) == 0) nv0[node] = fmaxf(-dem[node], 0.f);
  if (u < VN){
    int g = b*VN + u;
    u32 pos = atomicAdd(&cnt[g], 1u);
    if (pos < CAP){
      FU fu; fu.f = nw;
      uint2 rec; rec.x = fu.u; rec.y = (u32)(node & (VN-1));
      bucket[(size_t)g*CAP + pos] = rec;
    }
  }
}

// ================= solver iteration: bucket gather (no atomics) =================
__global__ __launch_bounds__(256) void k_gather(
    const u32* __restrict__ cnt, const uint2* __restrict__ bucket,
    const float* __restrict__ dem, const float* __restrict__ nvin, float* __restrict__ nvout)
{
  int tid = blockIdx.x*256 + threadIdx.x;
  int g = tid >> 4;          // target slot 0..65535
  int lane = tid & 15;
  int b = g >> 14;
  u32 n = cnt[g];
  if (n > CAP) n = CAP;
  const uint2* bk = bucket + (size_t)g*CAP;
  const float* nb = nvin + (size_t)b*VN;
  float sum = 0.f;
  for (u32 i = (u32)lane; i < n; i += 16u){
    uint2 r = bk[i];
    FU fu; fu.u = r.x;
    sum += fu.f * nb[r.y];
  }
  #pragma unroll
  for (int sh=1; sh<16; sh<<=1) sum += __shfl_xor(sum, sh, 64);
  if (lane == 0) nvout[g] = fmaxf(sum - dem[g], 0.f);
}

// ========= flow + pflow materialization in one pass (+ cost) =========
__global__ __launch_bounds__(256) void k_flows(
    const float* __restrict__ normw, const float* __restrict__ nv9,
    const float* __restrict__ nv10,
    float* __restrict__ pflow, float* __restrict__ flow, float* __restrict__ cost)
{
  int e = blockIdx.x*256 + threadIdx.x;
  int node = e >> 4;
  float w = normw[e];
  pflow[e] = w * nv9[node];
  float fl = w * nv10[node];
  flow[e] = fl;
  float ss = fl*fl;
  #pragma unroll
  for (int sh=1; sh<64; sh<<=1) ss += __shfl_xor(ss, sh, 64);
  __shared__ float part[4];
  if ((threadIdx.x & 63) == 0) part[threadIdx.x>>6] = ss;
  __syncthreads();
  if (threadIdx.x == 0) atomicAdd(cost + (e>>18), part[0]+part[1]+part[2]+part[3]);
}

// ================= launcher =================
extern "C" void kernel_launch(void* const* d_in, const int* in_sizes, int n_in,
                              void* d_out, int out_size, void* d_ws, size_t ws_size,
                              hipStream_t stream)
{
  const float* emb  = (const float*)d_in[0];
  const float* feat = (const float*)d_in[1];
  const float* dem  = (const float*)d_in[2];
  const int*   adj  = (const int*)  d_in[3];
  const float* We1 = (const float*)d_in[6];
  const float* be1 = (const float*)d_in[7];
  const float* We2 = (const float*)d_in[8];
  const float* be2 = (const float*)d_in[9];
  const float* Wg  = (const float*)d_in[10];
  const float* asrc= (const float*)d_in[11];
  const float* adst= (const float*)d_in[12];
  const float* Wz  = (const float*)d_in[13];
  const float* Uz  = (const float*)d_in[14];
  const float* bz  = (const float*)d_in[15];
  const float* Wr  = (const float*)d_in[16];
  const float* Ur  = (const float*)d_in[17];
  const float* br  = (const float*)d_in[18];
  const float* Wc  = (const float*)d_in[19];
  const float* Uc  = (const float*)d_in[20];
  const float* bc  = (const float*)d_in[21];
  const float* Wd1 = (const float*)d_in[22];
  const float* bd1 = (const float*)d_in[23];
  const float* Wd2 = (const float*)d_in[24];
  const float* bd2 = (const float*)d_in[25];

  char* ws = (char*)d_ws;
  float* h     = (float*)(ws + OFF_H);
  u32*   tq    = (u32*)  (ws + OFF_T);          // fp8 t-table, [NN+1][64] u32
  uint2* bucket= (uint2*)(ws + OFF_T);          // overlays t after attn done
  float* m     = (float*)(ws + OFF_M);
  float* ssrc  = (float*)(ws + OFF_SSRC);
  float* sdst  = (float*)(ws + OFF_SDST);
  float* nodew = (float*)(ws + OFF_NW);
  float* nv    = (float*)(ws + OFF_NV);         // [2][NN]
  u32*   cnt   = (u32*)  (ws + OFF_CNT);
  u16* pg  = (u16*)(ws + OFF_PG);
  u16* pzr = (u16*)(ws + OFF_PZR);
  u16* pc  = (u16*)(ws + OFF_PC);
  u16* pe1 = (u16*)(ws + OFF_PE1);
  u16* pe2 = (u16*)(ws + OFF_PE2);
  u16* pd1 = (u16*)(ws + OFF_PD1);
  float* nv0b = nv;
  float* nv1b = nv + NN;

  float* out0 = (float*)d_out;            // flow   [B,V,K]  (= f10)
  float* out1 = out0 + 1048576;           // flow_cost [B]
  float* out2 = out0 + 1048580;           // norm_w [B,V,K]
  float* out3 = out0 + 2097156;           // pflow  [B,V,K]  (= f9)

  k_zero<<<256, 256, 0, stream>>>(cnt);
  k_pack<<<208, 256, 0, stream>>>(Wg, Wz, Uz, Wr, Ur, Wc, Uc, We1, We2, Wd1,
                                  pg, pzr, pc, pe1, pe2, pd1);
  k_enc<<<512, 128, 0, stream>>>(emb, feat, pe1, pe2, be1, be2, h);

  for (int l=0; l<2; ++l){
    k_t   <<<512, 128, 0, stream>>>(h, pg, asrc, adst, tq, ssrc, sdst);
    k_attn<<<16384, 256, 0, stream>>>(adj, tq, ssrc, sdst, m);
    k_gru <<<512, 128, 0, stream>>>(m, h, pzr, pc, bz, br, bc);
  }

  k_dec<<<512, 128, 0, stream>>>(h, pd1, bd1, Wd2, bd2, nodew, out1);
  // k_pw overwrites the t region as the inverse-adjacency bucket (t is dead now)
  k_pw <<<4096, 256, 0, stream>>>(adj, nodew, dem, out2, nv0b, cnt, bucket);

  // 10 gather iterations on node vectors (ping-pong nv0b/nv1b)
  for (int i=1; i<=10; ++i){
    float* in  = (i & 1) ? nv0b : nv1b;
    float* out = (i & 1) ? nv1b : nv0b;
    k_gather<<<4096, 256, 0, stream>>>(cnt, bucket, dem, in, out);
  }
  // pflow = normw*nv9 (nv1b), flow = normw*nv10 (nv0b), + cost — one pass
  k_flows<<<4096, 256, 0, stream>>>(out2, nv1b, nv0b, out3, out0, out1);
}

// Round 7
// 481.335 us; speedup vs baseline: 2.0771x; 1.0397x over previous
//
#include <hip/hip_runtime.h>
#include <stdint.h>
#include <math.h>

// Problem constants
#define BN 4
#define VN 16384
#define KN 16
#define HN 4
#define NN (BN*VN)          // 65536 nodes total
#define EN (VN*KN)          // 262144 edges per batch
#define CAP 64              // inverse-adjacency bucket capacity (P(deg>64) ~ 1e-13)
#define NEGC (-1.0e9f)

typedef __attribute__((ext_vector_type(8))) short short8;
typedef __attribute__((ext_vector_type(4))) float floatx4;
typedef __attribute__((ext_vector_type(2))) float floatx2;
typedef unsigned short u16;
typedef unsigned int u32;

// ---------- workspace layout (bytes) ----------
// h, m are bf16 now (8 MB each). t_all fp8 u32[NN+1][64] = 16.8 MB.
// Bucket u32[NN][64] = 16 MB overlays the t region (t dead before k_pw).
#define OFF_H      0ull                     // h       bf16 [NN][64]    8 MB
#define OFF_M      8388608ull               // m       bf16 [NN][64]    8 MB (PERMUTED dim order)
#define OFF_T      16777216ull              // t_all   fp8 u32[NN+1][64] 16.8 MB; REUSED as bucket u32[NN][64]
#define OFF_SSRC   50331648ull              // s_src   fp32 [NN][4]     1 MB
#define OFF_SDST   51380224ull              // s_dst   fp32 [NN][4]     1 MB
#define OFF_NW     52428800ull              // node_w  fp32 [NN]      256 KB
#define OFF_NV     52690944ull              // nv      fp32 [2][NN]   512 KB
#define OFF_CNT    53215232ull              // cnt     u32  [NN]      256 KB
#define OFF_PG     53477376ull              // packed W_gat   32 KB
#define OFF_PZR    (OFF_PG  + 32768ull)     // packed Wz|Wr/Uz|Ur 32 KB
#define OFF_PC     (OFF_PZR + 32768ull)     // packed Wc/Uc   16 KB
#define OFF_PE1    (OFF_PC  + 16384ull)     // packed W_enc1 (K padded to 64) 8 KB
#define OFF_PE2    (OFF_PE1 + 8192ull)      // packed W_enc2  8 KB
#define OFF_PD1    (OFF_PE2 + 8192ull)      // packed W_dec1  8 KB
// total ws use ~53.6 MB

__device__ __forceinline__ u16 f2bf(float x){
  union { float f; unsigned int u; } c; c.f = x;
  unsigned int r = c.u + 0x7fffu + ((c.u >> 16) & 1u);
  return (u16)(r >> 16);
}
__device__ __forceinline__ float bf2f(u32 s){
  union { unsigned int u; float f; } c; c.u = s << 16;
  return c.f;
}
__device__ __forceinline__ float sigm(float x){ return 1.0f/(1.0f+expf(-x)); }

union S8 { short8 v; u16 u[8]; };

// ================= weight pack kernel =================
// packed layout: flat elem e = ((ng*CN + c)*64 + lane)*8 + j holds Mat[k][n],
// k = c*32 + (lane>>4)*8 + j,  n = ng*16 + (lane&15),  CN = K/32.
// m is stored PERMUTED: m_perm[p] = m_std[(p&3)*16 + (p>>2)] -> un-permute m rows here.
__global__ __launch_bounds__(256) void k_pack(
    const float* __restrict__ Wg,  const float* __restrict__ Wz, const float* __restrict__ Uz,
    const float* __restrict__ Wr,  const float* __restrict__ Ur, const float* __restrict__ Wc,
    const float* __restrict__ Uc,  const float* __restrict__ We1, const float* __restrict__ We2,
    const float* __restrict__ Wd1,
    u16* __restrict__ pg, u16* __restrict__ pzr, u16* __restrict__ pc,
    u16* __restrict__ pe1, u16* __restrict__ pe2, u16* __restrict__ pd1)
{
  int e = blockIdx.x*256 + threadIdx.x;   // 0 .. 53247
  int el; u16* dst; int CN; int region;
  if      (e < 16384){ el = e;        dst = pg;  CN = 2; region = 0; }
  else if (e < 32768){ el = e-16384;  dst = pzr; CN = 4; region = 1; }
  else if (e < 40960){ el = e-32768;  dst = pc;  CN = 4; region = 2; }
  else if (e < 45056){ el = e-40960;  dst = pe1; CN = 2; region = 3; }
  else if (e < 49152){ el = e-45056;  dst = pe2; CN = 2; region = 4; }
  else               { el = e-49152;  dst = pd1; CN = 2; region = 5; }
  int j    = el & 7;
  int lane = (el >> 3) & 63;
  int rest = el >> 9;
  int c  = rest % CN;
  int ng = rest / CN;
  int k  = c*32 + (lane>>4)*8 + j;
  int n  = ng*16 + (lane&15);
  float val = 0.0f;
  if (region == 0){                 // W_gat [H][64][64], n = hd*64+d
    val = Wg[(size_t)(n>>6)*4096 + k*64 + (n&63)];
  } else if (region == 1){          // [m_perm|h] @ [[Wz Wr],[Uz Ur]]
    int km = (k&3)*16 + ((k>>2)&15);              // un-permute m row
    if (n < 64) val = (k<64) ? Wz[km*64+n]      : Uz[(k-64)*64+n];
    else        val = (k<64) ? Wr[km*64+(n-64)] : Ur[(k-64)*64+(n-64)];
  } else if (region == 2){          // [m_perm|r*h] @ [[Wc],[Uc]]
    int km = (k&3)*16 + ((k>>2)&15);
    val = (k<64) ? Wc[km*64+n] : Uc[(k-64)*64+n];
  } else if (region == 3){          // W_enc1 [34][64], K padded to 64 with zeros
    val = (k<34) ? We1[k*64+n] : 0.0f;
  } else if (region == 4){
    val = We2[k*64+n];
  } else {
    val = Wd1[k*64+n];
  }
  dst[el] = f2bf(val);
}

// ================= shared GEMM helpers =================
template<int CN>
__device__ __forceinline__ void load_b(const u16* p, int chunk, int lane, short8 Bf[CN][4]){
  const short8* P = (const short8*)p;
  #pragma unroll
  for (int c=0;c<CN;c++)
    #pragma unroll
    for (int ng=0; ng<4; ng++)
      Bf[c][ng] = P[((chunk*4+ng)*CN + c)*64 + lane];
}

template<int CN>
__device__ __forceinline__ void mfma_tile(const short8* A, const short8 Bf[CN][4],
                                          floatx4 acc[4][4], int wave, int lane){
  #pragma unroll
  for (int c=0;c<CN;c++){
    #pragma unroll
    for (int mg=0;mg<4;mg++){
      short8 a = A[((wave*4+mg)*CN + c)*64 + lane];
      #pragma unroll
      for (int ng=0;ng<4;ng++)
        acc[mg][ng] = __builtin_amdgcn_mfma_f32_16x16x32_bf16(a, Bf[c][ng], acc[mg][ng], 0, 0, 0);
    }
  }
}

__device__ __forceinline__ void zero_acc(floatx4 acc[4][4]){
  #pragma unroll
  for (int mg=0;mg<4;mg++)
    #pragma unroll
    for (int ng=0;ng<4;ng++){
      floatx4 z = {0.f,0.f,0.f,0.f};
      acc[mg][ng] = z;
    }
}

// ================= encoder (+ cnt zero-init, grid is exactly NN threads) ===========
__global__ __launch_bounds__(128) void k_enc(
    const float* __restrict__ emb, const float* __restrict__ feat,
    const u16* __restrict__ pe1, const u16* __restrict__ pe2,
    const float* __restrict__ be1, const float* __restrict__ be2,
    u16* __restrict__ hout, u32* __restrict__ cnt)
{
  cnt[blockIdx.x*128 + threadIdx.x] = 0u;
  __shared__ short8 A1[1024];
  __shared__ short8 A2[1024];
  const int tid = threadIdx.x;
  const int n0  = blockIdx.x * 128;
  for (int it=0; it<8; ++it){
    int slot = it*128 + tid;
    int row = slot >> 3, jc = slot & 7;
    S8 w;
    if (jc < 4){
      const float* s = emb + (size_t)(n0+row)*32 + jc*8;
      #pragma unroll
      for (int j=0;j<8;j++) w.u[j] = f2bf(s[j]);
    } else if (jc == 4){
      const float* s = feat + (size_t)(n0+row)*2;
      w.u[0] = f2bf(s[0]); w.u[1] = f2bf(s[1]);
      #pragma unroll
      for (int j=2;j<8;j++) w.u[j] = 0;
    } else {
      #pragma unroll
      for (int j=0;j<8;j++) w.u[j] = 0;
    }
    A1[((row>>4)*2 + (jc>>2))*64 + (jc&3)*16 + (row&15)] = w.v;
  }
  __syncthreads();
  const int wave = tid>>6, lane = tid&63, q = lane>>4, ml = lane&15;

  short8 Bf[2][4];
  load_b<2>(pe1, 0, lane, Bf);
  floatx4 acc[4][4];
  zero_acc(acc);
  mfma_tile<2>(A1, Bf, acc, wave, lane);

  u16* A2s = (u16*)A2;
  #pragma unroll
  for (int mg=0;mg<4;mg++){
    #pragma unroll
    for (int r=0;r<4;r++){
      int row_l = wave*64 + mg*16 + q*4 + r;
      #pragma unroll
      for (int ng=0;ng<4;ng++){
        int k2 = ng*16 + ml;
        float v = tanhf(acc[mg][ng][r] + be1[k2]);
        int c2 = k2>>5, q2=(k2>>3)&3, j2=k2&7;
        A2s[ (((row_l>>4)*2 + c2)*64 + q2*16 + (row_l&15))*8 + j2 ] = f2bf(v);
      }
    }
  }
  __syncthreads();

  load_b<2>(pe2, 0, lane, Bf);
  zero_acc(acc);
  mfma_tile<2>(A2, Bf, acc, wave, lane);
  #pragma unroll
  for (int mg=0;mg<4;mg++)
    #pragma unroll
    for (int r=0;r<4;r++){
      int row = n0 + wave*64 + mg*16 + q*4 + r;
      #pragma unroll
      for (int ng=0;ng<4;ng++){
        int col = ng*16 + ml;
        hout[(size_t)row*64 + col] = f2bf(tanhf(acc[mg][ng][r] + be2[col]));
      }
    }
}

// ===== t = h @ W_gat (4 heads) -> fp8 rows (permuted) + s_src/s_dst dots =====
// h bf16: staging is a straight short8 copy (one dwordx4 + one ds_write_b128).
__global__ __launch_bounds__(128) void k_t(
    const u16* __restrict__ h, const u16* __restrict__ pg,
    const float* __restrict__ asrc, const float* __restrict__ adst,
    u32* __restrict__ tq, float* __restrict__ ssrc, float* __restrict__ sdst)
{
  __shared__ short8 A[1024];
  const int tid = threadIdx.x;
  const int n0  = blockIdx.x * 128;
  const short8* hp = (const short8*)h;
  for (int it=0; it<8; ++it){
    int slot = it*128 + tid;
    int row = slot >> 3, jc = slot & 7;
    A[((row>>4)*2 + (jc>>2))*64 + (jc&3)*16 + (row&15)] = hp[(size_t)(n0+row)*8 + jc];
  }
  __syncthreads();
  const int wave = tid>>6, lane = tid&63, q = lane>>4, ml = lane&15;

  for (int chunk=0; chunk<4; ++chunk){       // chunk == head
    short8 Bf[2][4];
    load_b<2>(pg, chunk, lane, Bf);
    floatx4 acc[4][4];
    zero_acc(acc);
    mfma_tile<2>(A, Bf, acc, wave, lane);

    float as[4], ad[4];
    #pragma unroll
    for (int ng=0;ng<4;ng++){
      as[ng] = asrc[chunk*64 + ng*16 + ml];
      ad[ng] = adst[chunk*64 + ng*16 + ml];
    }
    #pragma unroll
    for (int mg=0;mg<4;mg++){
      #pragma unroll
      for (int r=0;r<4;r++){
        int row = n0 + wave*64 + mg*16 + q*4 + r;
        float v0 = acc[mg][0][r], v1 = acc[mg][1][r];
        float v2 = acc[mg][2][r], v3 = acc[mg][3][r];
        int pk = __builtin_amdgcn_cvt_pk_fp8_f32(v0, v1, 0, false);
        pk     = __builtin_amdgcn_cvt_pk_fp8_f32(v2, v3, pk, true);
        tq[(size_t)row*64 + chunk*16 + ml] = (u32)pk;
        float ps = v0*as[0] + v1*as[1] + v2*as[2] + v3*as[3];
        float pd = v0*ad[0] + v1*ad[1] + v2*ad[2] + v3*ad[3];
        #pragma unroll
        for (int s=1;s<16;s<<=1){ ps += __shfl_xor(ps, s, 64); pd += __shfl_xor(pd, s, 64); }
        if (ml == 0){ ssrc[row*4 + chunk] = ps; sdst[row*4 + chunk] = pd; }
      }
    }
  }
}

// ================= attention + aggregate + tanh(m), m stored bf16 permuted ==========
__global__ __launch_bounds__(256) void k_attn(
    const int* __restrict__ adj, const u32* __restrict__ tq,
    const float* __restrict__ ssrc, const float* __restrict__ sdst,
    u16* __restrict__ m)
{
  const int wave = threadIdx.x>>6, lane = threadIdx.x&63;
  const int nid = blockIdx.x*4 + wave;
  const int b = nid >> 14;
  const int hd = lane>>4;
  int u = adj[(size_t)nid*16 + (lane&15)];
  float sc = (u == VN) ? NEGC : (ssrc[nid*4 + hd] + sdst[((size_t)b*VN + u)*4 + hd]);
  float mx = sc;
  #pragma unroll
  for (int s=1;s<16;s<<=1) mx = fmaxf(mx, __shfl_xor(mx, s, 64));
  float ex = expf(sc - mx);
  float sm = ex;
  #pragma unroll
  for (int s=1;s<16;s<<=1) sm += __shfl_xor(sm, s, 64);
  float attn = ex / sm;

  float a0=0.f, a1=0.f, a2=0.f, a3=0.f;
  const int srcl = lane & 48;
  #pragma unroll
  for (int k2=0;k2<16;k2++){
    int u2 = __shfl(u, k2, 64);             // wave-uniform
    float av = __shfl(attn, srcl + k2, 64); // this head's weight for neighbor k2
    u32 w = tq[((size_t)b*VN + u2)*64 + lane];
    floatx2 f01 = __builtin_amdgcn_cvt_pk_f32_fp8((int)w, false);
    floatx2 f23 = __builtin_amdgcn_cvt_pk_f32_fp8((int)w, true);
    a0 += av*f01.x; a1 += av*f01.y; a2 += av*f23.x; a3 += av*f23.y;
  }
  a0 += __shfl_xor(a0,16,64); a0 += __shfl_xor(a0,32,64);
  a1 += __shfl_xor(a1,16,64); a1 += __shfl_xor(a1,32,64);
  a2 += __shfl_xor(a2,16,64); a2 += __shfl_xor(a2,32,64);
  a3 += __shfl_xor(a3,16,64); a3 += __shfl_xor(a3,32,64);
  if (lane < 16){
    // m in PERMUTED dim order: m[nid*64 + 4*ml + j] = agg[std col j*16+ml]
    union { uint2 v; u16 u[4]; } val;
    val.u[0] = f2bf(tanhf(a0*0.25f)); val.u[1] = f2bf(tanhf(a1*0.25f));
    val.u[2] = f2bf(tanhf(a2*0.25f)); val.u[3] = f2bf(tanhf(a3*0.25f));
    *(uint2*)(m + (size_t)nid*64 + lane*4) = val.v;
  }
}

// ================= fused GRU (h, m bf16) =================
__global__ __launch_bounds__(128) void k_gru(
    const u16* __restrict__ m, u16* __restrict__ h,
    const u16* __restrict__ pzr, const u16* __restrict__ pc_,
    const float* __restrict__ bz, const float* __restrict__ br,
    const float* __restrict__ bc_)
{
  __shared__ short8 A[2048];
  const int tid = threadIdx.x;
  const int n0  = blockIdx.x * 128;
  const short8* mp = (const short8*)m;
  const short8* hp = (const short8*)h;
  for (int it=0; it<16; ++it){
    int slot = it*128 + tid;
    int row = slot >> 4, jc = slot & 15;
    short8 w = (jc < 8) ? mp[(size_t)(n0+row)*8 + jc]
                        : hp[(size_t)(n0+row)*8 + (jc-8)];
    A[((row>>4)*4 + (jc>>2))*64 + (jc&3)*16 + (row&15)] = w;
  }
  __syncthreads();
  const int wave = tid>>6, lane = tid&63, q = lane>>4, ml = lane&15;

  short8 Bf[4][4];

  // ---- z (chunk 0) on original [m|h] ----
  floatx4 zacc[4][4];
  load_b<4>(pzr, 0, lane, Bf);
  zero_acc(zacc);
  mfma_tile<4>(A, Bf, zacc, wave, lane);

  // ---- r (chunk 1) on original [m|h] ----
  floatx4 acc[4][4];
  load_b<4>(pzr, 1, lane, Bf);
  zero_acc(acc);
  mfma_tile<4>(A, Bf, acc, wave, lane);

  // overwrite h-half of own rows with r*h; save h_old in regs
  floatx4 h_old[4][4];
  u16* As = (u16*)A;
  #pragma unroll
  for (int mg=0;mg<4;mg++){
    #pragma unroll
    for (int r=0;r<4;r++){
      int row_l = wave*64 + mg*16 + q*4 + r;
      int row   = n0 + row_l;
      #pragma unroll
      for (int ng=0;ng<4;ng++){
        int col = ng*16 + ml;
        float rv = sigm(acc[mg][ng][r] + br[col]);
        float hv = bf2f(h[(size_t)row*64 + col]);
        h_old[mg][ng][r] = hv;
        int kk = 64 + col;
        int c2 = kk>>5, q2 = (kk>>3)&3, j2 = kk&7;
        As[ (((row_l>>4)*4 + c2)*64 + q2*16 + (row_l&15))*8 + j2 ] = f2bf(hv*rv);
      }
    }
  }
  // no __syncthreads: each wave rewrote only its own rows' fragments and the
  // MFMA below reads only this wave's rows (lgkmcnt orders LDS ops).

  // ---- c (pc chunk 0) on [m | r*h] ----
  load_b<4>(pc_, 0, lane, Bf);
  zero_acc(acc);
  mfma_tile<4>(A, Bf, acc, wave, lane);

  #pragma unroll
  for (int mg=0;mg<4;mg++)
    #pragma unroll
    for (int r=0;r<4;r++){
      int row = n0 + wave*64 + mg*16 + q*4 + r;
      #pragma unroll
      for (int ng=0;ng<4;ng++){
        int col = ng*16 + ml;
        float zv = sigm(zacc[mg][ng][r] + bz[col]);
        float cv = tanhf(acc[mg][ng][r] + bc_[col]);
        float ho = h_old[mg][ng][r];
        h[(size_t)row*64 + col] = f2bf((1.f - zv)*ho + zv*cv);
      }
    }
}

// ================= decoder + zero-init of cost =================
__global__ __launch_bounds__(128) void k_dec(
    const u16* __restrict__ h, const u16* __restrict__ pd1,
    const float* __restrict__ bd1, const float* __restrict__ Wd2, const float* __restrict__ bd2,
    float* __restrict__ nodew, float* __restrict__ cost)
{
  {
    int t = blockIdx.x*128 + threadIdx.x;
    if (t < BN) cost[t] = 0.f;
  }
  __shared__ short8 A[1024];
  const int tid = threadIdx.x;
  const int n0  = blockIdx.x * 128;
  const short8* hp = (const short8*)h;
  for (int it=0; it<8; ++it){
    int slot = it*128 + tid;
    int row = slot >> 3, jc = slot & 7;
    A[((row>>4)*2 + (jc>>2))*64 + (jc&3)*16 + (row&15)] = hp[(size_t)(n0+row)*8 + jc];
  }
  __syncthreads();
  const int wave = tid>>6, lane = tid&63, q = lane>>4, ml = lane&15;

  short8 Bf[2][4];
  load_b<2>(pd1, 0, lane, Bf);
  floatx4 acc[4][4];
  zero_acc(acc);
  mfma_tile<2>(A, Bf, acc, wave, lane);

  float wd2l[4];
  #pragma unroll
  for (int ng=0;ng<4;ng++) wd2l[ng] = Wd2[ng*16 + ml];
  float b2 = bd2[0];
  #pragma unroll
  for (int mg=0;mg<4;mg++)
    #pragma unroll
    for (int r=0;r<4;r++){
      int row = n0 + wave*64 + mg*16 + q*4 + r;
      float ps = 0.f;
      #pragma unroll
      for (int ng=0;ng<4;ng++)
        ps += tanhf(acc[mg][ng][r] + bd1[ng*16+ml]) * wd2l[ng];
      #pragma unroll
      for (int s=1;s<16;s<<=1) ps += __shfl_xor(ps, s, 64);
      if (ml == 0) nodew[row] = ps + b2;
    }
}

// ===== edge softmax + nv0 + INLINE inverse-adjacency bucket build =====
// record u32 = bf16(norm_w)<<16 | src_node (14 bits). Contiguous per target ->
// halved scattered-line write traffic vs uint2.
__global__ __launch_bounds__(256) void k_pw(
    const int* __restrict__ adj, const float* __restrict__ nodew, const float* __restrict__ dem,
    float* __restrict__ normw, float* __restrict__ nv0,
    u32* __restrict__ cnt, u32* __restrict__ bucket)
{
  int e = blockIdx.x*256 + threadIdx.x;
  int node = e >> 4;
  int b = node >> 14;
  int u = adj[e];
  float pw = (u == VN) ? NEGC : nodew[(size_t)b*VN + u];
  float mx = pw;
  #pragma unroll
  for (int s=1;s<16;s<<=1) mx = fmaxf(mx, __shfl_xor(mx, s, 64));
  float ex = expf(pw - mx);
  float sm = ex;
  #pragma unroll
  for (int s=1;s<16;s<<=1) sm += __shfl_xor(sm, s, 64);
  float nw = ex / sm;
  normw[e] = nw;
  if ((e & 15) == 0) nv0[node] = fmaxf(-dem[node], 0.f);
  if (u < VN){
    int g = b*VN + u;
    u32 pos = atomicAdd(&cnt[g], 1u);
    if (pos < CAP)
      bucket[(size_t)g*CAP + pos] = ((u32)f2bf(nw) << 16) | (u32)(node & (VN-1));
  }
}

// ================= solver iteration: bucket gather (no atomics) =================
__global__ __launch_bounds__(256) void k_gather(
    const u32* __restrict__ cnt, const u32* __restrict__ bucket,
    const float* __restrict__ dem, const float* __restrict__ nvin, float* __restrict__ nvout)
{
  int tid = blockIdx.x*256 + threadIdx.x;
  int g = tid >> 4;          // target slot 0..65535
  int lane = tid & 15;
  int b = g >> 14;
  u32 n = cnt[g];
  if (n > CAP) n = CAP;
  const u32* bk = bucket + (size_t)g*CAP;
  const float* nb = nvin + (size_t)b*VN;
  float sum = 0.f;
  for (u32 i = (u32)lane; i < n; i += 16u){
    u32 r = bk[i];
    sum += bf2f(r >> 16) * nb[r & 0xFFFFu];
  }
  #pragma unroll
  for (int sh=1; sh<16; sh<<=1) sum += __shfl_xor(sum, sh, 64);
  if (lane == 0) nvout[g] = fmaxf(sum - dem[g], 0.f);
}

// ========= flow + pflow materialization in one pass (+ cost) =========
__global__ __launch_bounds__(256) void k_flows(
    const float* __restrict__ normw, const float* __restrict__ nv9,
    const float* __restrict__ nv10,
    float* __restrict__ pflow, float* __restrict__ flow, float* __restrict__ cost)
{
  int e = blockIdx.x*256 + threadIdx.x;
  int node = e >> 4;
  float w = normw[e];
  pflow[e] = w * nv9[node];
  float fl = w * nv10[node];
  flow[e] = fl;
  float ss = fl*fl;
  #pragma unroll
  for (int sh=1; sh<64; sh<<=1) ss += __shfl_xor(ss, sh, 64);
  __shared__ float part[4];
  if ((threadIdx.x & 63) == 0) part[threadIdx.x>>6] = ss;
  __syncthreads();
  if (threadIdx.x == 0) atomicAdd(cost + (e>>18), part[0]+part[1]+part[2]+part[3]);
}

// ================= launcher =================
extern "C" void kernel_launch(void* const* d_in, const int* in_sizes, int n_in,
                              void* d_out, int out_size, void* d_ws, size_t ws_size,
                              hipStream_t stream)
{
  const float* emb  = (const float*)d_in[0];
  const float* feat = (const float*)d_in[1];
  const float* dem  = (const float*)d_in[2];
  const int*   adj  = (const int*)  d_in[3];
  const float* We1 = (const float*)d_in[6];
  const float* be1 = (const float*)d_in[7];
  const float* We2 = (const float*)d_in[8];
  const float* be2 = (const float*)d_in[9];
  const float* Wg  = (const float*)d_in[10];
  const float* asrc= (const float*)d_in[11];
  const float* adst= (const float*)d_in[12];
  const float* Wz  = (const float*)d_in[13];
  const float* Uz  = (const float*)d_in[14];
  const float* bz  = (const float*)d_in[15];
  const float* Wr  = (const float*)d_in[16];
  const float* Ur  = (const float*)d_in[17];
  const float* br  = (const float*)d_in[18];
  const float* Wc  = (const float*)d_in[19];
  const float* Uc  = (const float*)d_in[20];
  const float* bc  = (const float*)d_in[21];
  const float* Wd1 = (const float*)d_in[22];
  const float* bd1 = (const float*)d_in[23];
  const float* Wd2 = (const float*)d_in[24];
  const float* bd2 = (const float*)d_in[25];

  char* ws = (char*)d_ws;
  u16*   h     = (u16*)  (ws + OFF_H);
  u16*   m     = (u16*)  (ws + OFF_M);
  u32*   tq    = (u32*)  (ws + OFF_T);          // fp8 t-table, [NN+1][64] u32
  u32*   bucket= (u32*)  (ws + OFF_T);          // overlays t after attn done
  float* ssrc  = (float*)(ws + OFF_SSRC);
  float* sdst  = (float*)(ws + OFF_SDST);
  float* nodew = (float*)(ws + OFF_NW);
  float* nv    = (float*)(ws + OFF_NV);         // [2][NN]
  u32*   cnt   = (u32*)  (ws + OFF_CNT);
  u16* pg  = (u16*)(ws + OFF_PG);
  u16* pzr = (u16*)(ws + OFF_PZR);
  u16* pc  = (u16*)(ws + OFF_PC);
  u16* pe1 = (u16*)(ws + OFF_PE1);
  u16* pe2 = (u16*)(ws + OFF_PE2);
  u16* pd1 = (u16*)(ws + OFF_PD1);
  float* nv0b = nv;
  float* nv1b = nv + NN;

  float* out0 = (float*)d_out;            // flow   [B,V,K]  (= f10)
  float* out1 = out0 + 1048576;           // flow_cost [B]
  float* out2 = out0 + 1048580;           // norm_w [B,V,K]
  float* out3 = out0 + 2097156;           // pflow  [B,V,K]  (= f9)

  k_pack<<<208, 256, 0, stream>>>(Wg, Wz, Uz, Wr, Ur, Wc, Uc, We1, We2, Wd1,
                                  pg, pzr, pc, pe1, pe2, pd1);
  k_enc<<<512, 128, 0, stream>>>(emb, feat, pe1, pe2, be1, be2, h, cnt);

  for (int l=0; l<2; ++l){
    k_t   <<<512, 128, 0, stream>>>(h, pg, asrc, adst, tq, ssrc, sdst);
    k_attn<<<16384, 256, 0, stream>>>(adj, tq, ssrc, sdst, m);
    k_gru <<<512, 128, 0, stream>>>(m, h, pzr, pc, bz, br, bc);
  }

  k_dec<<<512, 128, 0, stream>>>(h, pd1, bd1, Wd2, bd2, nodew, out1);
  // k_pw overwrites the t region as the inverse-adjacency bucket (t is dead now)
  k_pw <<<4096, 256, 0, stream>>>(adj, nodew, dem, out2, nv0b, cnt, bucket);

  // 10 gather iterations on node vectors (ping-pong nv0b/nv1b)
  for (int i=1; i<=10; ++i){
    float* in  = (i & 1) ? nv0b : nv1b;
    float* out = (i & 1) ? nv1b : nv0b;
    k_gather<<<4096, 256, 0, stream>>>(cnt, bucket, dem, in, out);
  }
  // pflow = normw*nv9 (nv1b), flow = normw*nv10 (nv0b), + cost — one pass
  k_flows<<<4096, 256, 0, stream>>>(out2, nv1b, nv0b, out3, out0, out1);
}